// Round 1
// 782.511 us; speedup vs baseline: 1.0134x; 1.0134x over previous
//
#include <hip/hip_runtime.h>
#include <cstdint>

// LlamaAttention prefill: x[T,D] -> QKV gemm -> RoPE -> causal GQA flash attn -> O gemm
// T=4096 (B=4 x S=1024), D=4096, N=32 q-heads, K=8 kv-heads, H=128.
// All matmuls bf16 MFMA 16x16x32, fp32 accumulate. Workspace: 168 MB.
// This round: GEMMs upgraded to 256x256-tile 8-phase counted-vmcnt schedule
// (T2 LDS swizzle + T3/T4 phase pipeline + T5 setprio), replacing the 128^2
// 2-barrier structure that ceilings at ~950 TF.

typedef unsigned short u16;
typedef short bf16x8 __attribute__((ext_vector_type(8)));
typedef float f32x4 __attribute__((ext_vector_type(4)));

#define L2E 1.44269504088896340736f

static __device__ __forceinline__ u16 f2bf(float f) {
  union { float f; unsigned u; } v; v.f = f;
  unsigned r = (v.u + 0x7fffu + ((v.u >> 16) & 1u)) >> 16;
  return (u16)r;
}
static __device__ __forceinline__ float bf2f(u16 h) {
  union { unsigned u; float f; } v; v.u = ((unsigned)h) << 16;
  return v.f;
}

typedef __attribute__((address_space(1))) const unsigned int gas_u32;
typedef __attribute__((address_space(3))) unsigned int las_u32;
// async global->LDS, 16B per lane; LDS dest must be wave-uniform base (+lane*16).
static __device__ __forceinline__ void glds16(const void* g, const void* l) {
  __builtin_amdgcn_global_load_lds((gas_u32*)(uintptr_t)g,
                                   (las_u32*)(unsigned)(uintptr_t)l, 16, 0, 0);
}

// ---------------- fp32 -> bf16 elementwise ----------------
__global__ __launch_bounds__(256) void cvt_kernel(const float4* __restrict__ in,
                                                  uint2* __restrict__ out, int n4) {
  int i = blockIdx.x * 256 + threadIdx.x;
  if (i < n4) {
    float4 v = in[i];
    uint2 r;
    r.x = (unsigned)f2bf(v.x) | ((unsigned)f2bf(v.y) << 16);
    r.y = (unsigned)f2bf(v.z) | ((unsigned)f2bf(v.w) << 16);
    out[i] = r;
  }
}

// ---------------- fp32 [R][C] -> bf16 [C][R] tiled transpose ----------------
__global__ __launch_bounds__(256) void tcvt_kernel(const float* __restrict__ in,
                                                   u16* __restrict__ out, int R, int C) {
  __shared__ float tile[32][33];
  int tx = threadIdx.x, ty = threadIdx.y;  // block (32,8)
  int r0 = blockIdx.y * 32, c0 = blockIdx.x * 32;
#pragma unroll
  for (int j = 0; j < 4; ++j)
    tile[ty + j * 8][tx] = in[(size_t)(r0 + ty + j * 8) * C + c0 + tx];
  __syncthreads();
#pragma unroll
  for (int j = 0; j < 4; ++j)
    out[(size_t)(c0 + ty + j * 8) * R + r0 + tx] = f2bf(tile[tx][ty + j * 8]);
}

// ---------------- NT GEMM: C[M,N] = A[M,K] * B[N,K]^T (bf16 in, fp32 acc) --------
// 256x256 tile, BK=64 as two K=32 slabs, 512 thr = 8 waves (2M x 4N), per-wave
// 128x64 output (acc[8][4]). 8-phase schedule, 2 K-tiles/iteration:
//   phase (buf,ks,nh): { ds_read frags; stage 1 half-tile (2x glds); barrier;
//                        setprio(1); 16 MFMA; setprio(0); [vmcnt(6) @P4/P8]; barrier }
// LDS [buf][ks][256][32] bf16 (128 KiB), chunk-XOR swizzle phys = log ^ ((row>>1)&3)
// -> conflict-free ds_read_b128 (pre-swizzled global source, linear glds dest).
// Staging ledger (iteration computing tiles t=2i in buf0, t+1 in buf1):
//   P1:B(t+1,ks1)  P2:A(t+2,ks0)  P3:B(t+2,ks0)  P4:A(t+2,ks1)+vmcnt(6)
//   P5:B(t+2,ks1)  P6:A(t+3,ks0)  P7:B(t+3,ks0)  P8:A(t+3,ks1)+vmcnt(6)
// Every staged slab's last reader finished >=1 barrier earlier; every consumed
// slab's staging is >=3 phases old at the covering vmcnt(6) (3 half-tiles in flight).
template <int BF16OUT>
__global__ __launch_bounds__(512, 2) void gemm_nt8(const u16* __restrict__ A,
                                                   const u16* __restrict__ Bm,
                                                   void* __restrict__ Cp,
                                                   int M, int N, int Kd) {
  __shared__ u16 Als[2][2][8192];  // [buf][ks][row*32+col], 64 KiB
  __shared__ u16 Bls[2][2][8192];  // 64 KiB
  const int tid = threadIdx.x;
  const int w = tid >> 6, lane = tid & 63;
  const int ln15 = lane & 15, quad = lane >> 4;
  const int wm = w & 1, wn = w >> 1;  // 2 x 4 wave grid

  // XCD-aware swizzle (nwg % 8 == 0 for all our shapes)
  const int nbm = M >> 8;
  const int nwg = nbm * (N >> 8);
  const int cpx = nwg >> 3;
  const int bid = blockIdx.x;
  const int swz = (bid & 7) * cpx + (bid >> 3);
  const int bm = swz & (nbm - 1);
  const int bn = swz / nbm;
  const int m0 = bm << 8, n0 = bn << 8;

  const int nt = Kd >> 6;  // K-tiles (even; K multiple of 128)

  // staging: wave w instr h covers rows w*32+h*16+(lane>>2), chunk lane&3;
  // source chunk pre-swizzled so linear LDS dest yields swizzled layout.
  const int srow = lane >> 2;
  const int schk = ((lane & 3) ^ ((lane >> 3) & 3)) << 3;  // elements
  const u16* aSrc = A + (size_t)(m0 + w * 32 + srow) * Kd + schk;
  const u16* bSrc = Bm + (size_t)(n0 + w * 32 + srow) * Kd + schk;
  const int ldsb = w * 1024;  // element offset of wave's staging rows (w*32 rows)

  // LDS read offsets (elements): row*32 + swizzled chunk; swizzle term is
  // lane-constant across fragments (row base always multiple of 16).
  const int rswz = (quad ^ ((ln15 >> 1) & 3)) << 3;
  const int aoff = (wm * 128 + ln15) * 32 + rswz;
  const int boff = (wn * 64 + ln15) * 32 + rswz;

  f32x4 acc[8][4];
#pragma unroll
  for (int i = 0; i < 8; ++i)
#pragma unroll
    for (int j = 0; j < 4; ++j) acc[i][j] = f32x4{0.f, 0.f, 0.f, 0.f};
  bf16x8 af[8];

#define STA(kt, buf, ks)                                          \
  do {                                                            \
    int kc_ = (kt) < nt ? (kt) : nt - 1;                          \
    const u16* s_ = aSrc + (size_t)kc_ * 64 + (ks) * 32;          \
    glds16(s_, &Als[buf][ks][ldsb]);                              \
    glds16(s_ + (size_t)16 * Kd, &Als[buf][ks][ldsb + 512]);      \
  } while (0)
#define STB(kt, buf, ks)                                          \
  do {                                                            \
    int kc_ = (kt) < nt ? (kt) : nt - 1;                          \
    const u16* s_ = bSrc + (size_t)kc_ * 64 + (ks) * 32;          \
    glds16(s_, &Bls[buf][ks][ldsb]);                              \
    glds16(s_ + (size_t)16 * Kd, &Bls[buf][ks][ldsb + 512]);      \
  } while (0)

#define PHASE(buf, ks, nh, STAGE, VM)                                              \
  do {                                                                             \
    if ((nh) == 0) {                                                               \
      _Pragma("unroll") for (int m_ = 0; m_ < 8; ++m_)                             \
          af[m_] = *(const bf16x8*)&Als[buf][ks][aoff + m_ * 512];                 \
    }                                                                              \
    bf16x8 b0_ = *(const bf16x8*)&Bls[buf][ks][boff + (nh) * 1024];                \
    bf16x8 b1_ = *(const bf16x8*)&Bls[buf][ks][boff + (nh) * 1024 + 512];          \
    STAGE;                                                                         \
    __builtin_amdgcn_s_barrier();                                                  \
    __builtin_amdgcn_s_setprio(1);                                                 \
    _Pragma("unroll") for (int m_ = 0; m_ < 8; ++m_) {                             \
      acc[m_][2 * (nh)] =                                                          \
          __builtin_amdgcn_mfma_f32_16x16x32_bf16(af[m_], b0_, acc[m_][2 * (nh)],  \
                                                  0, 0, 0);                        \
      acc[m_][2 * (nh) + 1] = __builtin_amdgcn_mfma_f32_16x16x32_bf16(             \
          af[m_], b1_, acc[m_][2 * (nh) + 1], 0, 0, 0);                            \
    }                                                                              \
    __builtin_amdgcn_s_setprio(0);                                                 \
    if (VM) asm volatile("s_waitcnt vmcnt(6)" ::: "memory");                       \
    __builtin_amdgcn_s_barrier();                                                  \
    __builtin_amdgcn_sched_barrier(0);                                             \
  } while (0)

  // prologue: tile0 fully + 3 half-tiles of tile1; vmcnt(6) drains tile0.
  STA(0, 0, 0); STB(0, 0, 0); STA(0, 0, 1); STB(0, 0, 1);
  STA(1, 1, 0); STB(1, 1, 0); STA(1, 1, 1);
  asm volatile("s_waitcnt vmcnt(6)" ::: "memory");
  __builtin_amdgcn_s_barrier();
  __builtin_amdgcn_sched_barrier(0);

  const int iters = nt >> 1;
  for (int i = 0; i < iters; ++i) {
    const int t = 2 * i;
    PHASE(0, 0, 0, STB(t + 1, 1, 1), 0);
    PHASE(0, 0, 1, STA(t + 2, 0, 0), 0);
    PHASE(0, 1, 0, STB(t + 2, 0, 0), 0);
    PHASE(0, 1, 1, STA(t + 2, 0, 1), 1);
    PHASE(1, 0, 0, STB(t + 2, 0, 1), 0);
    PHASE(1, 0, 1, STA(t + 3, 1, 0), 0);
    PHASE(1, 1, 0, STB(t + 3, 1, 0), 0);
    PHASE(1, 1, 1, STA(t + 3, 1, 1), 1);
  }
#undef PHASE
#undef STA
#undef STB

  // epilogue: C-write (no LDS use)
  const int crow = m0 + wm * 128 + quad * 4;
  const int ccol = n0 + wn * 64 + ln15;
#pragma unroll
  for (int m = 0; m < 8; ++m)
#pragma unroll
    for (int j = 0; j < 4; ++j)
#pragma unroll
      for (int r = 0; r < 4; ++r) {
        float v = acc[m][j][r];
        if (BF16OUT)
          ((u16*)Cp)[(size_t)(crow + m * 16 + r) * N + ccol + j * 16] = f2bf(v);
        else
          ((float*)Cp)[(size_t)(crow + m * 16 + r) * N + ccol + j * 16] = v;
      }
}

// ---------------- RoPE in-place on q (cols 0..4095) and k (cols 4096..5119) ------
// Also folds softmax scale 1/sqrt(128) into q.
__global__ __launch_bounds__(256) void rope_kernel(u16* __restrict__ qkv,
                                                   const int* __restrict__ pos, int total) {
  int idx = blockIdx.x * 256 + threadIdx.x;
  if (idx >= total) return;          // total = T * 40 * 64
  int t = idx / 2560;
  int rem = idx - t * 2560;
  int head = rem >> 6;               // 0..39 (32 q heads + 8 k heads)
  int i = rem & 63;                  // rotation pair index
  float p = (float)pos[t];
  // theta^{-2i/H} = 2^(-i * log2(10000)/64)
  float inv = exp2f(-0.20751874963942190927f * (float)i);
  float f = p * inv;
  float s, c;
  sincosf(f, &s, &c);
  int colbase = (head < 32) ? head * 128 : (4096 + (head - 32) * 128);
  u16* base = qkv + (size_t)t * 6144 + colbase;
  float x1 = bf2f(base[i]), x2 = bf2f(base[i + 64]);
  float o1 = x1 * c - x2 * s;
  float o2 = x2 * c + x1 * s;
  if (head < 32) { o1 *= 0.08838834764831845f; o2 *= 0.08838834764831845f; }
  base[i] = f2bf(o1);
  base[i + 64] = f2bf(o2);
}

// ---------------- Flash attention, causal, GQA ----------------
// grid = B*N*(S/64); block 256 = 4 waves; wave w owns q-rows w*16..w*16+15.
// K tile [64][128] via swizzled global_load_lds; V tile transposed [128][72] via
// vectorized global b128 loads + conflict-free packed b32 LDS writes;
// online softmax in registers (rows live in 16-lane quads); P->LDS->A-layout for PV.
__global__ __launch_bounds__(256, 3) void attn_kernel(const u16* __restrict__ qkv,
                                                      u16* __restrict__ outp) {
  __shared__ u16 Klds[64 * 128];
  __shared__ u16 Vtlds[128 * 72];
  __shared__ u16 Plds[4 * 16 * 72];

  const int bx = blockIdx.x;
  const int qb = 15 - (bx & 15);     // heavy (large-qb) blocks dispatch first
  const int n = (bx >> 4) & 31;
  const int b = bx >> 9;
  const int kh = n >> 2;             // GQA: 4 q heads per kv head

  const int tid = threadIdx.x;
  const int w = tid >> 6;
  const int lane = tid & 63;
  const int ln15 = lane & 15;
  const int quad = lane >> 4;

  const int ldq = 6144;
  const int seq0 = b << 10;
  const int q0 = seq0 + qb * 64;

  const u16* Qg = qkv + n * 128;
  const u16* Kg = qkv + 4096 + kh * 128;
  const u16* Vg = qkv + 5120 + kh * 128;

  // Q fragments (A-layout: m=ln15, k=quad*8+j), q pre-scaled in rope
  bf16x8 qf[4];
  {
    const u16* qrow = Qg + (size_t)(q0 + w * 16 + ln15) * ldq + quad * 8;
#pragma unroll
    for (int ks = 0; ks < 4; ++ks) qf[ks] = *(const bf16x8*)(qrow + ks * 32);
  }

  f32x4 o[8];
#pragma unroll
  for (int i = 0; i < 8; ++i) o[i] = f32x4{0.f, 0.f, 0.f, 0.f};
  float m_r[4] = {-INFINITY, -INFINITY, -INFINITY, -INFINITY};
  float l_r[4] = {0.f, 0.f, 0.f, 0.f};

  const int krow = w * 4 + (lane >> 4);
  const int kcol = (((lane & 15) ^ (krow & 7)) << 3);

  // V staging geometry: lane covers rows (s0, s0+1) x 16 h's starting at hb
  const int vs0 = (lane & 31) * 2;
  const int vhb = w * 32 + (lane >> 5) * 16;

  for (int kt = 0; kt <= qb; ++kt) {
    __syncthreads();  // previous tile fully consumed
    {
      const u16* kbase = Kg + (size_t)(seq0 + kt * 64 + krow) * ldq + kcol;
#pragma unroll
      for (int q = 0; q < 4; ++q)
        glds16(kbase + (size_t)q * 16 * ldq, &Klds[(q * 16 + w * 4) * 128]);
    }
    {
      // V transpose: vector global loads -> packed pair writes (2 lanes/bank = free)
      const u16* v0 = Vg + (size_t)(seq0 + kt * 64 + vs0) * ldq + vhb;
      union { uint4 v[2]; u16 s[16]; } ra, rb;
      ra.v[0] = *(const uint4*)v0;
      ra.v[1] = *(const uint4*)(v0 + 8);
      rb.v[0] = *(const uint4*)(v0 + ldq);
      rb.v[1] = *(const uint4*)(v0 + ldq + 8);
#pragma unroll
      for (int j = 0; j < 16; ++j) {
        unsigned pk = (unsigned)ra.s[j] | ((unsigned)rb.s[j] << 16);
        *(unsigned*)&Vtlds[(vhb + j) * 72 + vs0] = pk;
      }
    }
    __syncthreads();  // tiles visible (drains vmcnt for global_load_lds)

    // S = Q K^T : 16x64 per wave
    f32x4 sfr[4];
#pragma unroll
    for (int c = 0; c < 4; ++c) {
      f32x4 acc = f32x4{0.f, 0.f, 0.f, 0.f};
#pragma unroll
      for (int ks = 0; ks < 4; ++ks) {
        int rr = c * 16 + ln15;
        int ph = (ks * 4 + quad) ^ (rr & 7);
        bf16x8 kf = *(const bf16x8*)&Klds[rr * 128 + ph * 8];
        acc = __builtin_amdgcn_mfma_f32_16x16x32_bf16(qf[ks], kf, acc, 0, 0, 0);
      }
      sfr[c] = acc;
    }

    if (kt == qb) {  // diagonal tile: mask col>row (offsets cancel)
#pragma unroll
      for (int c = 0; c < 4; ++c) {
        int col = c * 16 + ln15;
#pragma unroll
        for (int r = 0; r < 4; ++r)
          if (col > w * 16 + quad * 4 + r) sfr[c][r] = -INFINITY;
      }
    }

    // online softmax; row (quad*4+r) spans the 16 lanes of a quad
    float alpha[4];
#pragma unroll
    for (int r = 0; r < 4; ++r) {
      float mx = fmaxf(fmaxf(sfr[0][r], sfr[1][r]), fmaxf(sfr[2][r], sfr[3][r]));
      mx = fmaxf(mx, __shfl_xor(mx, 1));
      mx = fmaxf(mx, __shfl_xor(mx, 2));
      mx = fmaxf(mx, __shfl_xor(mx, 4));
      mx = fmaxf(mx, __shfl_xor(mx, 8));
      float mnew = fmaxf(m_r[r], mx);
      alpha[r] = exp2f((m_r[r] - mnew) * L2E);
      m_r[r] = mnew;
      float rs = 0.f;
#pragma unroll
      for (int c = 0; c < 4; ++c) {
        float pv = exp2f((sfr[c][r] - mnew) * L2E);
        sfr[c][r] = pv;
        rs += pv;
      }
      rs += __shfl_xor(rs, 1);
      rs += __shfl_xor(rs, 2);
      rs += __shfl_xor(rs, 4);
      rs += __shfl_xor(rs, 8);
      l_r[r] = alpha[r] * l_r[r] + rs;
    }

#pragma unroll
    for (int ht = 0; ht < 8; ++ht)
#pragma unroll
      for (int r = 0; r < 4; ++r) o[ht][r] *= alpha[r];

    // P: C-layout -> LDS -> A-layout (bf16)
#pragma unroll
    for (int c = 0; c < 4; ++c)
#pragma unroll
      for (int r = 0; r < 4; ++r)
        Plds[w * 1152 + (quad * 4 + r) * 72 + c * 16 + ln15] = f2bf(sfr[c][r]);

    asm volatile("s_waitcnt lgkmcnt(0)" ::: "memory");

    bf16x8 pf[2];
#pragma unroll
    for (int ks = 0; ks < 2; ++ks)
      pf[ks] = *(const bf16x8*)&Plds[w * 1152 + ln15 * 72 + ks * 32 + quad * 8];
#pragma unroll
    for (int ht = 0; ht < 8; ++ht) {
#pragma unroll
      for (int ks = 0; ks < 2; ++ks) {
        bf16x8 vf = *(const bf16x8*)&Vtlds[(ht * 16 + ln15) * 72 + ks * 32 + quad * 8];
        o[ht] = __builtin_amdgcn_mfma_f32_16x16x32_bf16(pf[ks], vf, o[ht], 0, 0, 0);
      }
    }
  }

#pragma unroll
  for (int r = 0; r < 4; ++r) l_r[r] = 1.f / l_r[r];
#pragma unroll
  for (int ht = 0; ht < 8; ++ht)
#pragma unroll
    for (int r = 0; r < 4; ++r)
      outp[(size_t)(q0 + w * 16 + quad * 4 + r) * 4096 + n * 128 + ht * 16 + ln15] =
          f2bf(o[ht][r] * l_r[r]);
}

// ---------------- host ----------------
extern "C" void kernel_launch(void* const* d_in, const int* in_sizes, int n_in,
                              void* d_out, int out_size, void* d_ws, size_t ws_size,
                              hipStream_t stream) {
  const float* x = (const float*)d_in[0];
  const int* posi = (const int*)d_in[1];
  const float* Wq = (const float*)d_in[2];
  const float* Wk = (const float*)d_in[3];
  const float* Wv = (const float*)d_in[4];
  const float* Wo = (const float*)d_in[5];
  float* out = (float*)d_out;
  char* ws = (char*)d_ws;

  // workspace layout (bytes); attn reuses xb region (disjoint lifetimes). 168 MB total.
  u16* xb = (u16*)(ws);                         // [4096][4096] bf16, 33.5 MB
  u16* Wt = (u16*)(ws + 33554432);              // [6144][4096] bf16 (Wq^T|Wk^T|Wv^T), 50.3 MB
  u16* WoT = (u16*)(ws + 83886080);             // [4096][4096] bf16 (Wo^T), 33.5 MB
  u16* qkv = (u16*)(ws + 117440512);            // [4096][6144] bf16, 50.3 MB
  u16* attn = xb;                               // [4096][4096] bf16 (after x consumed)

  cvt_kernel<<<16384, 256, 0, stream>>>((const float4*)x, (uint2*)xb, 4194304);
  tcvt_kernel<<<dim3(128, 128), dim3(32, 8), 0, stream>>>(Wq, Wt, 4096, 4096);
  tcvt_kernel<<<dim3(32, 128), dim3(32, 8), 0, stream>>>(Wk, Wt + (size_t)4096 * 4096, 4096, 1024);
  tcvt_kernel<<<dim3(32, 128), dim3(32, 8), 0, stream>>>(Wv, Wt + (size_t)5120 * 4096, 4096, 1024);
  tcvt_kernel<<<dim3(128, 128), dim3(32, 8), 0, stream>>>(Wo, WoT, 4096, 4096);

  gemm_nt8<1><<<dim3(384), 512, 0, stream>>>(xb, Wt, qkv, 4096, 6144, 4096);
  rope_kernel<<<40960, 256, 0, stream>>>(qkv, posi, 10485760);
  attn_kernel<<<2048, 256, 0, stream>>>(qkv, attn);
  gemm_nt8<0><<<dim3(256), 512, 0, stream>>>(attn, WoT, out, 4096, 4096, 4096);
}

// Round 2
// 750.333 us; speedup vs baseline: 1.0568x; 1.0429x over previous
//
#include <hip/hip_runtime.h>
#include <cstdint>

// LlamaAttention prefill: x[T,D] -> QKV gemm -> RoPE -> causal GQA flash attn -> O gemm
// T=4096 (B=4 x S=1024), D=4096, N=32 q-heads, K=8 kv-heads, H=128.
// All matmuls bf16 MFMA 16x16x32, fp32 accumulate.
// Round 2: GEMM fragment loads converted to inline-asm ds_read_b128 (opaque to the
// backend waitcnt pass -> no auto vmcnt drain per phase; counted vmcnt(6) now governs),
// attn V-prefetch (T14 issue-early/write-late) + defer-max (T13), RoPE sincos table.

typedef unsigned short u16;
typedef short bf16x8 __attribute__((ext_vector_type(8)));
typedef float f32x4 __attribute__((ext_vector_type(4)));

#define L2E 1.44269504088896340736f

static __device__ __forceinline__ u16 f2bf(float f) {
  union { float f; unsigned u; } v; v.f = f;
  unsigned r = (v.u + 0x7fffu + ((v.u >> 16) & 1u)) >> 16;
  return (u16)r;
}
static __device__ __forceinline__ float bf2f(u16 h) {
  union { unsigned u; float f; } v; v.u = ((unsigned)h) << 16;
  return v.f;
}

typedef __attribute__((address_space(1))) const unsigned int gas_u32;
typedef __attribute__((address_space(3))) unsigned int las_u32;
// async global->LDS, 16B per lane; LDS dest must be wave-uniform base (+lane*16).
static __device__ __forceinline__ void glds16(const void* g, const void* l) {
  __builtin_amdgcn_global_load_lds((gas_u32*)(uintptr_t)g,
                                   (las_u32*)(unsigned)(uintptr_t)l, 16, 0, 0);
}

// ---------------- fp32 -> bf16 elementwise ----------------
__global__ __launch_bounds__(256) void cvt_kernel(const float4* __restrict__ in,
                                                  uint2* __restrict__ out, int n4) {
  int i = blockIdx.x * 256 + threadIdx.x;
  if (i < n4) {
    float4 v = in[i];
    uint2 r;
    r.x = (unsigned)f2bf(v.x) | ((unsigned)f2bf(v.y) << 16);
    r.y = (unsigned)f2bf(v.z) | ((unsigned)f2bf(v.w) << 16);
    out[i] = r;
  }
}

// ---------------- fp32 [R][C] -> bf16 [C][R] tiled transpose ----------------
__global__ __launch_bounds__(256) void tcvt_kernel(const float* __restrict__ in,
                                                   u16* __restrict__ out, int R, int C) {
  __shared__ float tile[32][33];
  int tx = threadIdx.x, ty = threadIdx.y;  // block (32,8)
  int r0 = blockIdx.y * 32, c0 = blockIdx.x * 32;
#pragma unroll
  for (int j = 0; j < 4; ++j)
    tile[ty + j * 8][tx] = in[(size_t)(r0 + ty + j * 8) * C + c0 + tx];
  __syncthreads();
#pragma unroll
  for (int j = 0; j < 4; ++j)
    out[(size_t)(c0 + ty + j * 8) * R + r0 + tx] = f2bf(tile[tx][ty + j * 8]);
}

// ---------------- NT GEMM: C[M,N] = A[M,K] * B[N,K]^T (bf16 in, fp32 acc) --------
// 256x256 tile, BK=64 as two K=32 slabs, 512 thr = 8 waves (2M x 4N), per-wave
// 128x64 output (acc[8][4]). 8-phase counted-vmcnt schedule; fragment loads are
// inline-asm ds_read_b128 so the backend waitcnt pass cannot insert conservative
// vmcnt drains before them (the round-1 failure mode). Explicit lgkmcnt(0) +
// sched_barrier(0) before the MFMA cluster (rule #18).
// Staging ledger (iteration computing tiles t=2i in buf0, t+1 in buf1):
//   P1:B(t+1,ks1)  P2:A(t+2,ks0)  P3:B(t+2,ks0)  P4:A(t+2,ks1)+vmcnt(6)
//   P5:B(t+2,ks1)  P6:A(t+3,ks0)  P7:B(t+3,ks0)  P8:A(t+3,ks1)+vmcnt(6)
// Every staged slab's last reader finished >=1 barrier earlier; every consumed
// slab's staging is covered by the vmcnt(6) 3-half-tiles-in-flight invariant.
template <int BF16OUT>
__global__ __launch_bounds__(512, 2) void gemm_nt8(const u16* __restrict__ A,
                                                   const u16* __restrict__ Bm,
                                                   void* __restrict__ Cp,
                                                   int M, int N, int Kd) {
  __shared__ u16 Als[2][2][8192];  // [buf][ks][row*32+col], 64 KiB
  __shared__ u16 Bls[2][2][8192];  // 64 KiB
  const int tid = threadIdx.x;
  const int w = tid >> 6, lane = tid & 63;
  const int ln15 = lane & 15, quad = lane >> 4;
  const int wm = w & 1, wn = w >> 1;  // 2 x 4 wave grid

  // XCD-aware swizzle (nwg % 8 == 0 for all our shapes)
  const int nbm = M >> 8;
  const int nwg = nbm * (N >> 8);
  const int cpx = nwg >> 3;
  const int bid = blockIdx.x;
  const int swz = (bid & 7) * cpx + (bid >> 3);
  const int bm = swz & (nbm - 1);
  const int bn = swz / nbm;
  const int m0 = bm << 8, n0 = bn << 8;

  const int nt = Kd >> 6;  // K-tiles (even; K multiple of 128)

  // staging: wave w instr h covers rows w*32+h*16+(lane>>2), chunk lane&3;
  // source chunk pre-swizzled so linear LDS dest yields swizzled layout.
  const int srow = lane >> 2;
  const int schk = ((lane & 3) ^ ((lane >> 3) & 3)) << 3;  // elements
  const u16* aSrc = A + (size_t)(m0 + w * 32 + srow) * Kd + schk;
  const u16* bSrc = Bm + (size_t)(n0 + w * 32 + srow) * Kd + schk;
  const int ldsb = w * 1024;  // element offset of wave's staging rows (w*32 rows)

  // LDS read base addresses (byte): row*32 elems + swizzled chunk; swizzle key is
  // (row&15)>>1 which is invariant under the 16-row fragment steps.
  const int rswz = (quad ^ ((ln15 >> 1) & 3)) << 3;
  const int aoff = (wm * 128 + ln15) * 32 + rswz;
  const int boff = (wn * 64 + ln15) * 32 + rswz;
  const unsigned aAddr = (unsigned)(uintptr_t)&Als[0][0][aoff];
  const unsigned bAddr = (unsigned)(uintptr_t)&Bls[0][0][boff];

  f32x4 acc[8][4];
#pragma unroll
  for (int i = 0; i < 8; ++i)
#pragma unroll
    for (int j = 0; j < 4; ++j) acc[i][j] = f32x4{0.f, 0.f, 0.f, 0.f};
  bf16x8 af[8];

#define DSR(dst, addr, off) \
  asm volatile("ds_read_b128 %0, %1 offset:%2" : "=v"(dst) : "v"(addr), "i"(off))

#define STA(kt, buf, ks)                                          \
  do {                                                            \
    int kc_ = (kt) < nt ? (kt) : nt - 1;                          \
    const u16* s_ = aSrc + (size_t)kc_ * 64 + (ks) * 32;          \
    glds16(s_, &Als[buf][ks][ldsb]);                              \
    glds16(s_ + (size_t)16 * Kd, &Als[buf][ks][ldsb + 512]);      \
  } while (0)
#define STB(kt, buf, ks)                                          \
  do {                                                            \
    int kc_ = (kt) < nt ? (kt) : nt - 1;                          \
    const u16* s_ = bSrc + (size_t)kc_ * 64 + (ks) * 32;          \
    glds16(s_, &Bls[buf][ks][ldsb]);                              \
    glds16(s_ + (size_t)16 * Kd, &Bls[buf][ks][ldsb + 512]);      \
  } while (0)

#define PHASE(buf, ks, nh, STAGE, VM)                                              \
  do {                                                                             \
    if ((nh) == 0) {                                                               \
      DSR(af[0], aAddr, (buf)*32768 + (ks)*16384 + 0 * 1024);                      \
      DSR(af[1], aAddr, (buf)*32768 + (ks)*16384 + 1 * 1024);                      \
      DSR(af[2], aAddr, (buf)*32768 + (ks)*16384 + 2 * 1024);                      \
      DSR(af[3], aAddr, (buf)*32768 + (ks)*16384 + 3 * 1024);                      \
      DSR(af[4], aAddr, (buf)*32768 + (ks)*16384 + 4 * 1024);                      \
      DSR(af[5], aAddr, (buf)*32768 + (ks)*16384 + 5 * 1024);                      \
      DSR(af[6], aAddr, (buf)*32768 + (ks)*16384 + 6 * 1024);                      \
      DSR(af[7], aAddr, (buf)*32768 + (ks)*16384 + 7 * 1024);                      \
    }                                                                              \
    bf16x8 b0_, b1_;                                                               \
    DSR(b0_, bAddr, (buf)*32768 + (ks)*16384 + (nh)*2048);                         \
    DSR(b1_, bAddr, (buf)*32768 + (ks)*16384 + (nh)*2048 + 1024);                  \
    STAGE;                                                                         \
    __builtin_amdgcn_s_barrier();                                                  \
    asm volatile("s_waitcnt lgkmcnt(0)" ::: "memory");                             \
    __builtin_amdgcn_sched_barrier(0);                                             \
    __builtin_amdgcn_s_setprio(1);                                                 \
    _Pragma("unroll") for (int m_ = 0; m_ < 8; ++m_) {                             \
      acc[m_][2 * (nh)] =                                                          \
          __builtin_amdgcn_mfma_f32_16x16x32_bf16(af[m_], b0_, acc[m_][2 * (nh)],  \
                                                  0, 0, 0);                        \
      acc[m_][2 * (nh) + 1] = __builtin_amdgcn_mfma_f32_16x16x32_bf16(             \
          af[m_], b1_, acc[m_][2 * (nh) + 1], 0, 0, 0);                            \
    }                                                                              \
    __builtin_amdgcn_s_setprio(0);                                                 \
    if (VM) asm volatile("s_waitcnt vmcnt(6)" ::: "memory");                       \
    __builtin_amdgcn_s_barrier();                                                  \
    __builtin_amdgcn_sched_barrier(0);                                             \
  } while (0)

  // prologue: tile0 fully + 3 half-tiles of tile1; vmcnt(6) drains tile0.
  STA(0, 0, 0); STB(0, 0, 0); STA(0, 0, 1); STB(0, 0, 1);
  STA(1, 1, 0); STB(1, 1, 0); STA(1, 1, 1);
  asm volatile("s_waitcnt vmcnt(6)" ::: "memory");
  __builtin_amdgcn_s_barrier();
  __builtin_amdgcn_sched_barrier(0);

  const int iters = nt >> 1;
  for (int i = 0; i < iters; ++i) {
    const int t = 2 * i;
    PHASE(0, 0, 0, STB(t + 1, 1, 1), 0);
    PHASE(0, 0, 1, STA(t + 2, 0, 0), 0);
    PHASE(0, 1, 0, STB(t + 2, 0, 0), 0);
    PHASE(0, 1, 1, STA(t + 2, 0, 1), 1);
    PHASE(1, 0, 0, STB(t + 2, 0, 1), 0);
    PHASE(1, 0, 1, STA(t + 3, 1, 0), 0);
    PHASE(1, 1, 0, STB(t + 3, 1, 0), 0);
    PHASE(1, 1, 1, STA(t + 3, 1, 1), 1);
  }
#undef PHASE
#undef STA
#undef STB
#undef DSR

  // epilogue: C-write (no LDS use)
  const int crow = m0 + wm * 128 + quad * 4;
  const int ccol = n0 + wn * 64 + ln15;
#pragma unroll
  for (int m = 0; m < 8; ++m)
#pragma unroll
    for (int j = 0; j < 4; ++j)
#pragma unroll
      for (int r = 0; r < 4; ++r) {
        float v = acc[m][j][r];
        if (BF16OUT)
          ((u16*)Cp)[(size_t)(crow + m * 16 + r) * N + ccol + j * 16] = f2bf(v);
        else
          ((float*)Cp)[(size_t)(crow + m * 16 + r) * N + ccol + j * 16] = v;
      }
}

// ---------------- RoPE sincos table: tab[p*64+i] = (cos, sin) of p*theta^{-i/64} ----
__global__ __launch_bounds__(256) void ropetab_kernel(float2* __restrict__ tab) {
  int idx = blockIdx.x * 256 + threadIdx.x;  // 65536 = 1024 pos * 64 pairs
  int i = idx & 63;
  float inv = exp2f(-0.20751874963942190927f * (float)i);
  float f = (float)(idx >> 6) * inv;
  float s, c;
  sincosf(f, &s, &c);
  tab[idx] = make_float2(c, s);
}

// ---------------- RoPE in-place on q (cols 0..4095) and k (cols 4096..5119) ------
// Also folds softmax scale 1/sqrt(128) into q. Trig via precomputed table.
__global__ __launch_bounds__(256) void rope_kernel(u16* __restrict__ qkv,
                                                   const int* __restrict__ pos,
                                                   const float2* __restrict__ tab,
                                                   int total) {
  int idx = blockIdx.x * 256 + threadIdx.x;
  if (idx >= total) return;          // total = T * 40 * 64
  int t = idx / 2560;
  int rem = idx - t * 2560;
  int head = rem >> 6;               // 0..39 (32 q heads + 8 k heads)
  int i = rem & 63;                  // rotation pair index
  float2 cs = tab[(pos[t] << 6) | i];
  float c = cs.x, s = cs.y;
  int colbase = (head < 32) ? head * 128 : (4096 + (head - 32) * 128);
  u16* base = qkv + (size_t)t * 6144 + colbase;
  float x1 = bf2f(base[i]), x2 = bf2f(base[i + 64]);
  float o1 = x1 * c - x2 * s;
  float o2 = x2 * c + x1 * s;
  if (head < 32) { o1 *= 0.08838834764831845f; o2 *= 0.08838834764831845f; }
  base[i] = f2bf(o1);
  base[i + 64] = f2bf(o2);
}

// ---------------- Flash attention, causal, GQA ----------------
// grid = B*N*(S/64); block 256 = 4 waves; wave w owns q-rows w*16..w*16+15.
// K tile [64][128] via swizzled global_load_lds; V tile transposed [128][72]:
// T14 async-stage split — V(kt+1) global loads issued right after the second
// barrier (latency hides under compute), written to LDS after the next first
// barrier. Online softmax with T13 defer-max (skip rescale when growth <= 8).
__global__ __launch_bounds__(256, 3) void attn_kernel(const u16* __restrict__ qkv,
                                                      u16* __restrict__ outp) {
  __shared__ u16 Klds[64 * 128];
  __shared__ u16 Vtlds[128 * 72];
  __shared__ u16 Plds[4 * 16 * 72];

  const int bx = blockIdx.x;
  const int qb = 15 - (bx & 15);     // heavy (large-qb) blocks dispatch first
  const int n = (bx >> 4) & 31;
  const int b = bx >> 9;
  const int kh = n >> 2;             // GQA: 4 q heads per kv head

  const int tid = threadIdx.x;
  const int w = tid >> 6;
  const int lane = tid & 63;
  const int ln15 = lane & 15;
  const int quad = lane >> 4;

  const int ldq = 6144;
  const int seq0 = b << 10;
  const int q0 = seq0 + qb * 64;

  const u16* Qg = qkv + n * 128;
  const u16* Kg = qkv + 4096 + kh * 128;
  const u16* Vg = qkv + 5120 + kh * 128;

  // Q fragments (A-layout: m=ln15, k=quad*8+j), q pre-scaled in rope
  bf16x8 qf[4];
  {
    const u16* qrow = Qg + (size_t)(q0 + w * 16 + ln15) * ldq + quad * 8;
#pragma unroll
    for (int ks = 0; ks < 4; ++ks) qf[ks] = *(const bf16x8*)(qrow + ks * 32);
  }

  f32x4 o[8];
#pragma unroll
  for (int i = 0; i < 8; ++i) o[i] = f32x4{0.f, 0.f, 0.f, 0.f};
  float m_r[4] = {-INFINITY, -INFINITY, -INFINITY, -INFINITY};
  float l_r[4] = {0.f, 0.f, 0.f, 0.f};

  const int krow = w * 4 + (lane >> 4);
  const int kcol = (((lane & 15) ^ (krow & 7)) << 3);

  // V staging geometry: lane covers rows (s0, s0+1) x 16 h's starting at hb
  const int vs0 = (lane & 31) * 2;
  const int vhb = w * 32 + (lane >> 5) * 16;

  union V16 { uint4 v[2]; u16 s[16]; };
  V16 ra, rb;
  {  // prefetch V tile 0 into registers
    const u16* v0 = Vg + (size_t)(seq0 + vs0) * ldq + vhb;
    ra.v[0] = *(const uint4*)v0;
    ra.v[1] = *(const uint4*)(v0 + 8);
    rb.v[0] = *(const uint4*)(v0 + ldq);
    rb.v[1] = *(const uint4*)(v0 + ldq + 8);
  }

  for (int kt = 0; kt <= qb; ++kt) {
    __syncthreads();  // S1: previous tile consumed; drains V-reg prefetch loads
    {
      const u16* kbase = Kg + (size_t)(seq0 + kt * 64 + krow) * ldq + kcol;
#pragma unroll
      for (int q = 0; q < 4; ++q)
        glds16(kbase + (size_t)q * 16 * ldq, &Klds[(q * 16 + w * 4) * 128]);
    }
    {
      // V transpose write: packed pair writes (2 lanes/bank = free)
#pragma unroll
      for (int j = 0; j < 16; ++j) {
        unsigned pk = (unsigned)ra.s[j] | ((unsigned)rb.s[j] << 16);
        *(unsigned*)&Vtlds[(vhb + j) * 72 + vs0] = pk;
      }
    }
    __syncthreads();  // S2: tiles visible (drains vmcnt for global_load_lds)

    if (kt < qb) {  // T14: issue V(kt+1) loads now; latency hides under compute
      const u16* v0 = Vg + (size_t)(seq0 + (kt + 1) * 64 + vs0) * ldq + vhb;
      ra.v[0] = *(const uint4*)v0;
      ra.v[1] = *(const uint4*)(v0 + 8);
      rb.v[0] = *(const uint4*)(v0 + ldq);
      rb.v[1] = *(const uint4*)(v0 + ldq + 8);
    }

    // S = Q K^T : 16x64 per wave
    f32x4 sfr[4];
#pragma unroll
    for (int c = 0; c < 4; ++c) {
      f32x4 acc = f32x4{0.f, 0.f, 0.f, 0.f};
#pragma unroll
      for (int ks = 0; ks < 4; ++ks) {
        int rr = c * 16 + ln15;
        int ph = (ks * 4 + quad) ^ (rr & 7);
        bf16x8 kf = *(const bf16x8*)&Klds[rr * 128 + ph * 8];
        acc = __builtin_amdgcn_mfma_f32_16x16x32_bf16(qf[ks], kf, acc, 0, 0, 0);
      }
      sfr[c] = acc;
    }

    if (kt == qb) {  // diagonal tile: mask col>row (offsets cancel)
#pragma unroll
      for (int c = 0; c < 4; ++c) {
        int col = c * 16 + ln15;
#pragma unroll
        for (int r = 0; r < 4; ++r)
          if (col > w * 16 + quad * 4 + r) sfr[c][r] = -INFINITY;
      }
    }

    // online softmax; row (quad*4+r) spans the 16 lanes of a quad
    float mx[4];
#pragma unroll
    for (int r = 0; r < 4; ++r) {
      float m0 = fmaxf(fmaxf(sfr[0][r], sfr[1][r]), fmaxf(sfr[2][r], sfr[3][r]));
      m0 = fmaxf(m0, __shfl_xor(m0, 1));
      m0 = fmaxf(m0, __shfl_xor(m0, 2));
      m0 = fmaxf(m0, __shfl_xor(m0, 4));
      m0 = fmaxf(m0, __shfl_xor(m0, 8));
      mx[r] = m0;
    }
    // T13 defer-max: only rescale when some row's max grew by > 8 (P <= e^8)
    float ex = fmaxf(fmaxf(mx[0] - m_r[0], mx[1] - m_r[1]),
                     fmaxf(mx[2] - m_r[2], mx[3] - m_r[3]));
    if (!__all(ex <= 8.f)) {
#pragma unroll
      for (int r = 0; r < 4; ++r) {
        float mnew = fmaxf(m_r[r], mx[r]);
        float al = exp2f((m_r[r] - mnew) * L2E);
        m_r[r] = mnew;
        l_r[r] *= al;
#pragma unroll
        for (int ht = 0; ht < 8; ++ht) o[ht][r] *= al;
      }
    }
#pragma unroll
    for (int r = 0; r < 4; ++r) {
      float rs = 0.f;
#pragma unroll
      for (int c = 0; c < 4; ++c) {
        float pv = exp2f((sfr[c][r] - m_r[r]) * L2E);
        sfr[c][r] = pv;
        rs += pv;
      }
      rs += __shfl_xor(rs, 1);
      rs += __shfl_xor(rs, 2);
      rs += __shfl_xor(rs, 4);
      rs += __shfl_xor(rs, 8);
      l_r[r] += rs;
    }

    // P: C-layout -> LDS -> A-layout (bf16)
#pragma unroll
    for (int c = 0; c < 4; ++c)
#pragma unroll
      for (int r = 0; r < 4; ++r)
        Plds[w * 1152 + (quad * 4 + r) * 72 + c * 16 + ln15] = f2bf(sfr[c][r]);

    asm volatile("s_waitcnt lgkmcnt(0)" ::: "memory");

    bf16x8 pf[2];
#pragma unroll
    for (int ks = 0; ks < 2; ++ks)
      pf[ks] = *(const bf16x8*)&Plds[w * 1152 + ln15 * 72 + ks * 32 + quad * 8];
#pragma unroll
    for (int ht = 0; ht < 8; ++ht) {
#pragma unroll
      for (int ks = 0; ks < 2; ++ks) {
        bf16x8 vf = *(const bf16x8*)&Vtlds[(ht * 16 + ln15) * 72 + ks * 32 + quad * 8];
        o[ht] = __builtin_amdgcn_mfma_f32_16x16x32_bf16(pf[ks], vf, o[ht], 0, 0, 0);
      }
    }
  }

#pragma unroll
  for (int r = 0; r < 4; ++r) l_r[r] = 1.f / l_r[r];
#pragma unroll
  for (int ht = 0; ht < 8; ++ht)
#pragma unroll
    for (int r = 0; r < 4; ++r)
      outp[(size_t)(q0 + w * 16 + quad * 4 + r) * 4096 + n * 128 + ht * 16 + ln15] =
          f2bf(o[ht][r] * l_r[r]);
}

// ---------------- host ----------------
extern "C" void kernel_launch(void* const* d_in, const int* in_sizes, int n_in,
                              void* d_out, int out_size, void* d_ws, size_t ws_size,
                              hipStream_t stream) {
  const float* x = (const float*)d_in[0];
  const int* posi = (const int*)d_in[1];
  const float* Wq = (const float*)d_in[2];
  const float* Wk = (const float*)d_in[3];
  const float* Wv = (const float*)d_in[4];
  const float* Wo = (const float*)d_in[5];
  float* out = (float*)d_out;
  char* ws = (char*)d_ws;

  // workspace layout (bytes); attn reuses xb region (disjoint lifetimes). 168 MB total.
  u16* xb = (u16*)(ws);                         // [4096][4096] bf16, 33.5 MB
  u16* Wt = (u16*)(ws + 33554432);              // [6144][4096] bf16 (Wq^T|Wk^T|Wv^T), 50.3 MB
  u16* WoT = (u16*)(ws + 83886080);             // [4096][4096] bf16 (Wo^T), 33.5 MB
  u16* qkv = (u16*)(ws + 117440512);            // [4096][6144] bf16, 50.3 MB
  u16* attn = xb;                               // [4096][4096] bf16 (after x consumed)
  float2* rtab = (float2*)ws;                   // 512 KB sincos table; lives in the dead
                                                // window of xb (after QKV gemm reads xb,
                                                // before attn writes it)

  cvt_kernel<<<16384, 256, 0, stream>>>((const float4*)x, (uint2*)xb, 4194304);
  tcvt_kernel<<<dim3(128, 128), dim3(32, 8), 0, stream>>>(Wq, Wt, 4096, 4096);
  tcvt_kernel<<<dim3(32, 128), dim3(32, 8), 0, stream>>>(Wk, Wt + (size_t)4096 * 4096, 4096, 1024);
  tcvt_kernel<<<dim3(32, 128), dim3(32, 8), 0, stream>>>(Wv, Wt + (size_t)5120 * 4096, 4096, 1024);
  tcvt_kernel<<<dim3(128, 128), dim3(32, 8), 0, stream>>>(Wo, WoT, 4096, 4096);

  gemm_nt8<1><<<dim3(384), 512, 0, stream>>>(xb, Wt, qkv, 4096, 6144, 4096);
  ropetab_kernel<<<256, 256, 0, stream>>>(rtab);
  rope_kernel<<<40960, 256, 0, stream>>>(qkv, posi, rtab, 10485760);
  attn_kernel<<<2048, 256, 0, stream>>>(qkv, attn);
  gemm_nt8<0><<<dim3(256), 512, 0, stream>>>(attn, WoT, out, 4096, 4096, 4096);
}

// Round 4
// 687.592 us; speedup vs baseline: 1.1533x; 1.0912x over previous
//
#include <hip/hip_runtime.h>
#include <cstdint>

// LlamaAttention prefill: x[T,D] -> QKV gemm -> RoPE -> causal GQA flash attn -> O gemm
// T=4096 (B=4 x S=1024), D=4096, N=32 q-heads, K=8 kv-heads, H=128.
// Round 3 (resubmit; round-3 bench was an infra timeout): GQA-grouped attention —
// one 8-wave block per (seq, kv-head, q-tile) covering all 4 q-heads of the group;
// K/V staged once instead of 4x; K LDS double-buffer with cross-tile glds prefetch.
// GEMMs unchanged from round 2.

typedef unsigned short u16;
typedef short bf16x8 __attribute__((ext_vector_type(8)));
typedef float f32x4 __attribute__((ext_vector_type(4)));

#define L2E 1.44269504088896340736f

static __device__ __forceinline__ u16 f2bf(float f) {
  union { float f; unsigned u; } v; v.f = f;
  unsigned r = (v.u + 0x7fffu + ((v.u >> 16) & 1u)) >> 16;
  return (u16)r;
}
static __device__ __forceinline__ float bf2f(u16 h) {
  union { unsigned u; float f; } v; v.u = ((unsigned)h) << 16;
  return v.f;
}

typedef __attribute__((address_space(1))) const unsigned int gas_u32;
typedef __attribute__((address_space(3))) unsigned int las_u32;
// async global->LDS, 16B per lane; LDS dest must be wave-uniform base (+lane*16).
static __device__ __forceinline__ void glds16(const void* g, const void* l) {
  __builtin_amdgcn_global_load_lds((gas_u32*)(uintptr_t)g,
                                   (las_u32*)(unsigned)(uintptr_t)l, 16, 0, 0);
}

// ---------------- fp32 -> bf16 elementwise ----------------
__global__ __launch_bounds__(256) void cvt_kernel(const float4* __restrict__ in,
                                                  uint2* __restrict__ out, int n4) {
  int i = blockIdx.x * 256 + threadIdx.x;
  if (i < n4) {
    float4 v = in[i];
    uint2 r;
    r.x = (unsigned)f2bf(v.x) | ((unsigned)f2bf(v.y) << 16);
    r.y = (unsigned)f2bf(v.z) | ((unsigned)f2bf(v.w) << 16);
    out[i] = r;
  }
}

// ---------------- fp32 [R][C] -> bf16 [C][R] tiled transpose ----------------
__global__ __launch_bounds__(256) void tcvt_kernel(const float* __restrict__ in,
                                                   u16* __restrict__ out, int R, int C) {
  __shared__ float tile[32][33];
  int tx = threadIdx.x, ty = threadIdx.y;  // block (32,8)
  int r0 = blockIdx.y * 32, c0 = blockIdx.x * 32;
#pragma unroll
  for (int j = 0; j < 4; ++j)
    tile[ty + j * 8][tx] = in[(size_t)(r0 + ty + j * 8) * C + c0 + tx];
  __syncthreads();
#pragma unroll
  for (int j = 0; j < 4; ++j)
    out[(size_t)(c0 + ty + j * 8) * R + r0 + tx] = f2bf(tile[tx][ty + j * 8]);
}

// ---------------- NT GEMM: C[M,N] = A[M,K] * B[N,K]^T (bf16 in, fp32 acc) --------
// 256x256 tile, BK=64 as two K=32 slabs, 512 thr = 8 waves (2M x 4N), per-wave
// 128x64 output (acc[8][4]). 8-phase counted-vmcnt schedule (stable since r1;
// per-block ~1205 TF; QKV's 229us is the 384-blocks/256-CU 2-round quantization).
template <int BF16OUT>
__global__ __launch_bounds__(512, 2) void gemm_nt8(const u16* __restrict__ A,
                                                   const u16* __restrict__ Bm,
                                                   void* __restrict__ Cp,
                                                   int M, int N, int Kd) {
  __shared__ u16 Als[2][2][8192];  // [buf][ks][row*32+col], 64 KiB
  __shared__ u16 Bls[2][2][8192];  // 64 KiB
  const int tid = threadIdx.x;
  const int w = tid >> 6, lane = tid & 63;
  const int ln15 = lane & 15, quad = lane >> 4;
  const int wm = w & 1, wn = w >> 1;  // 2 x 4 wave grid

  // XCD-aware swizzle (nwg % 8 == 0 for all our shapes)
  const int nbm = M >> 8;
  const int nwg = nbm * (N >> 8);
  const int cpx = nwg >> 3;
  const int bid = blockIdx.x;
  const int swz = (bid & 7) * cpx + (bid >> 3);
  const int bm = swz & (nbm - 1);
  const int bn = swz / nbm;
  const int m0 = bm << 8, n0 = bn << 8;

  const int nt = Kd >> 6;  // K-tiles (even; K multiple of 128)

  // staging: wave w instr h covers rows w*32+h*16+(lane>>2), chunk lane&3;
  // source chunk pre-swizzled so linear LDS dest yields swizzled layout.
  const int srow = lane >> 2;
  const int schk = ((lane & 3) ^ ((lane >> 3) & 3)) << 3;  // elements
  const u16* aSrc = A + (size_t)(m0 + w * 32 + srow) * Kd + schk;
  const u16* bSrc = Bm + (size_t)(n0 + w * 32 + srow) * Kd + schk;
  const int ldsb = w * 1024;  // element offset of wave's staging rows (w*32 rows)

  // LDS read base addresses: row*32 elems + swizzled chunk; swizzle key is
  // (row&15)>>1 which is invariant under the 16-row fragment steps.
  const int rswz = (quad ^ ((ln15 >> 1) & 3)) << 3;
  const int aoff = (wm * 128 + ln15) * 32 + rswz;
  const int boff = (wn * 64 + ln15) * 32 + rswz;
  const unsigned aAddr = (unsigned)(uintptr_t)&Als[0][0][aoff];
  const unsigned bAddr = (unsigned)(uintptr_t)&Bls[0][0][boff];

  f32x4 acc[8][4];
#pragma unroll
  for (int i = 0; i < 8; ++i)
#pragma unroll
    for (int j = 0; j < 4; ++j) acc[i][j] = f32x4{0.f, 0.f, 0.f, 0.f};
  bf16x8 af[8];

#define DSR(dst, addr, off) \
  asm volatile("ds_read_b128 %0, %1 offset:%2" : "=v"(dst) : "v"(addr), "i"(off))

#define STA(kt, buf, ks)                                          \
  do {                                                            \
    int kc_ = (kt) < nt ? (kt) : nt - 1;                          \
    const u16* s_ = aSrc + (size_t)kc_ * 64 + (ks) * 32;          \
    glds16(s_, &Als[buf][ks][ldsb]);                              \
    glds16(s_ + (size_t)16 * Kd, &Als[buf][ks][ldsb + 512]);      \
  } while (0)
#define STB(kt, buf, ks)                                          \
  do {                                                            \
    int kc_ = (kt) < nt ? (kt) : nt - 1;                          \
    const u16* s_ = bSrc + (size_t)kc_ * 64 + (ks) * 32;          \
    glds16(s_, &Bls[buf][ks][ldsb]);                              \
    glds16(s_ + (size_t)16 * Kd, &Bls[buf][ks][ldsb + 512]);      \
  } while (0)

#define PHASE(buf, ks, nh, STAGE, VM)                                              \
  do {                                                                             \
    if ((nh) == 0) {                                                               \
      DSR(af[0], aAddr, (buf)*32768 + (ks)*16384 + 0 * 1024);                      \
      DSR(af[1], aAddr, (buf)*32768 + (ks)*16384 + 1 * 1024);                      \
      DSR(af[2], aAddr, (buf)*32768 + (ks)*16384 + 2 * 1024);                      \
      DSR(af[3], aAddr, (buf)*32768 + (ks)*16384 + 3 * 1024);                      \
      DSR(af[4], aAddr, (buf)*32768 + (ks)*16384 + 4 * 1024);                      \
      DSR(af[5], aAddr, (buf)*32768 + (ks)*16384 + 5 * 1024);                      \
      DSR(af[6], aAddr, (buf)*32768 + (ks)*16384 + 6 * 1024);                      \
      DSR(af[7], aAddr, (buf)*32768 + (ks)*16384 + 7 * 1024);                      \
    }                                                                              \
    bf16x8 b0_, b1_;                                                               \
    DSR(b0_, bAddr, (buf)*32768 + (ks)*16384 + (nh)*2048);                         \
    DSR(b1_, bAddr, (buf)*32768 + (ks)*16384 + (nh)*2048 + 1024);                  \
    STAGE;                                                                         \
    __builtin_amdgcn_s_barrier();                                                  \
    asm volatile("s_waitcnt lgkmcnt(0)" ::: "memory");                             \
    __builtin_amdgcn_sched_barrier(0);                                             \
    __builtin_amdgcn_s_setprio(1);                                                 \
    _Pragma("unroll") for (int m_ = 0; m_ < 8; ++m_) {                             \
      acc[m_][2 * (nh)] =                                                          \
          __builtin_amdgcn_mfma_f32_16x16x32_bf16(af[m_], b0_, acc[m_][2 * (nh)],  \
                                                  0, 0, 0);                        \
      acc[m_][2 * (nh) + 1] = __builtin_amdgcn_mfma_f32_16x16x32_bf16(             \
          af[m_], b1_, acc[m_][2 * (nh) + 1], 0, 0, 0);                            \
    }                                                                              \
    __builtin_amdgcn_s_setprio(0);                                                 \
    if (VM) asm volatile("s_waitcnt vmcnt(6)" ::: "memory");                       \
    __builtin_amdgcn_s_barrier();                                                  \
    __builtin_amdgcn_sched_barrier(0);                                             \
  } while (0)

  // prologue: tile0 fully + 3 half-tiles of tile1; vmcnt(6) drains tile0.
  STA(0, 0, 0); STB(0, 0, 0); STA(0, 0, 1); STB(0, 0, 1);
  STA(1, 1, 0); STB(1, 1, 0); STA(1, 1, 1);
  asm volatile("s_waitcnt vmcnt(6)" ::: "memory");
  __builtin_amdgcn_s_barrier();
  __builtin_amdgcn_sched_barrier(0);

  const int iters = nt >> 1;
  for (int i = 0; i < iters; ++i) {
    const int t = 2 * i;
    PHASE(0, 0, 0, STB(t + 1, 1, 1), 0);
    PHASE(0, 0, 1, STA(t + 2, 0, 0), 0);
    PHASE(0, 1, 0, STB(t + 2, 0, 0), 0);
    PHASE(0, 1, 1, STA(t + 2, 0, 1), 1);
    PHASE(1, 0, 0, STB(t + 2, 0, 1), 0);
    PHASE(1, 0, 1, STA(t + 3, 1, 0), 0);
    PHASE(1, 1, 0, STB(t + 3, 1, 0), 0);
    PHASE(1, 1, 1, STA(t + 3, 1, 1), 1);
  }
#undef PHASE
#undef STA
#undef STB
#undef DSR

  // epilogue: C-write (no LDS use)
  const int crow = m0 + wm * 128 + quad * 4;
  const int ccol = n0 + wn * 64 + ln15;
#pragma unroll
  for (int m = 0; m < 8; ++m)
#pragma unroll
    for (int j = 0; j < 4; ++j)
#pragma unroll
      for (int r = 0; r < 4; ++r) {
        float v = acc[m][j][r];
        if (BF16OUT)
          ((u16*)Cp)[(size_t)(crow + m * 16 + r) * N + ccol + j * 16] = f2bf(v);
        else
          ((float*)Cp)[(size_t)(crow + m * 16 + r) * N + ccol + j * 16] = v;
      }
}

// ---------------- RoPE sincos table: tab[p*64+i] = (cos, sin) of p*theta^{-i/64} ----
__global__ __launch_bounds__(256) void ropetab_kernel(float2* __restrict__ tab) {
  int idx = blockIdx.x * 256 + threadIdx.x;  // 65536 = 1024 pos * 64 pairs
  int i = idx & 63;
  float inv = exp2f(-0.20751874963942190927f * (float)i);
  float f = (float)(idx >> 6) * inv;
  float s, c;
  sincosf(f, &s, &c);
  tab[idx] = make_float2(c, s);
}

// ---------------- RoPE in-place on q (cols 0..4095) and k (cols 4096..5119) ------
// Also folds softmax scale 1/sqrt(128) into q. Trig via precomputed table.
__global__ __launch_bounds__(256) void rope_kernel(u16* __restrict__ qkv,
                                                   const int* __restrict__ pos,
                                                   const float2* __restrict__ tab,
                                                   int total) {
  int idx = blockIdx.x * 256 + threadIdx.x;
  if (idx >= total) return;          // total = T * 40 * 64
  int t = idx / 2560;
  int rem = idx - t * 2560;
  int head = rem >> 6;               // 0..39 (32 q heads + 8 k heads)
  int i = rem & 63;                  // rotation pair index
  float2 cs = tab[(pos[t] << 6) | i];
  float c = cs.x, s = cs.y;
  int colbase = (head < 32) ? head * 128 : (4096 + (head - 32) * 128);
  u16* base = qkv + (size_t)t * 6144 + colbase;
  float x1 = bf2f(base[i]), x2 = bf2f(base[i + 64]);
  float o1 = x1 * c - x2 * s;
  float o2 = x2 * c + x1 * s;
  if (head < 32) { o1 *= 0.08838834764831845f; o2 *= 0.08838834764831845f; }
  base[i] = f2bf(o1);
  base[i + 64] = f2bf(o2);
}

// ---------------- Flash attention, causal, GQA-grouped ----------------
// grid = 512 = 16 qb-tiles x 8 kv-heads x 4 seqs, globally qb-descending.
// Block = 512 thr = 8 waves = one full GQA group (4 q-heads x 64 q-rows);
// wave w: head w&3, row-half w>>2 (32 rows = 2 fragments of 16).
// K [2][64][128] LDS double-buffer, staged once per tile for all 4 heads via
// swizzled glds; K(kt+1) prefetch issued after S2 (latency hides under compute,
// next S1's vmcnt(0) is the covering wait). V reg-prefetch (T14) -> transposed
// [128][72] LDS write. Online softmax with defer-max (T13). P->LDS per wave.
__global__ __launch_bounds__(512, 2) void attn_kernel(const u16* __restrict__ qkv,
                                                      u16* __restrict__ outp) {
  __shared__ u16 Klds[2][64 * 128];   // 32 KB
  __shared__ u16 Vtlds[128 * 72];     // 18 KB
  __shared__ u16 Plds[8 * 32 * 72];   // 36 KB (per-wave 32 rows)

  const int bx = blockIdx.x;
  const int qb = 15 - (bx >> 5);      // global heavy-first ordering
  const int kh = bx & 7;
  const int b = (bx >> 3) & 3;

  const int tid = threadIdx.x;
  const int w = tid >> 6;             // 0..7
  const int lane = tid & 63;
  const int ln15 = lane & 15;
  const int quad = lane >> 4;
  const int g = w & 3;                // q-head within group
  const int half = w >> 2;            // row half (0/1)
  const int n = kh * 4 + g;

  const int ldq = 6144;
  const int seq0 = b << 10;
  const int q0 = seq0 + qb * 64;

  const u16* Qg = qkv + n * 128;
  const u16* Kg = qkv + 4096 + kh * 128;
  const u16* Vg = qkv + 5120 + kh * 128;

  // Q fragments: rf in {0,1}; A-layout row m=ln15, k=quad*8+j (q pre-scaled in rope)
  bf16x8 qf[2][4];
#pragma unroll
  for (int rf = 0; rf < 2; ++rf) {
    const u16* qrow = Qg + (size_t)(q0 + half * 32 + rf * 16 + ln15) * ldq + quad * 8;
#pragma unroll
    for (int ks = 0; ks < 4; ++ks) qf[rf][ks] = *(const bf16x8*)(qrow + ks * 32);
  }

  f32x4 o[2][8];
#pragma unroll
  for (int rf = 0; rf < 2; ++rf)
#pragma unroll
    for (int i = 0; i < 8; ++i) o[rf][i] = f32x4{0.f, 0.f, 0.f, 0.f};
  float m_r[2][4], l_r[2][4];
#pragma unroll
  for (int rf = 0; rf < 2; ++rf)
#pragma unroll
    for (int r = 0; r < 4; ++r) { m_r[rf][r] = -INFINITY; l_r[rf][r] = 0.f; }

  // K staging: wave w covers rows w*8 + q*4 + (lane>>4), q in {0,1}; chunk-XOR
  // pre-swizzle on the global source so the linear glds dest is swizzled.
  const int kr0 = w * 8 + (lane >> 4);
  const int kr1 = kr0 + 4;
  const u16* kp0 = Kg + (size_t)(seq0 + kr0) * ldq + (((lane & 15) ^ (kr0 & 7)) << 3);
  const u16* kp1 = Kg + (size_t)(seq0 + kr1) * ldq + (((lane & 15) ^ (kr1 & 7)) << 3);

  // V staging: thread covers rows (vs0, vs0+1) x 8 h-cols starting at vhb
  const int vs0 = (tid & 31) * 2;
  const int vhb = (tid >> 5) * 8;

  union V8 { uint4 v; u16 s[8]; };
  V8 ra, rb;
  {  // prefetch V tile 0 + stage K tile 0
    const u16* v0 = Vg + (size_t)(seq0 + vs0) * ldq + vhb;
    ra.v = *(const uint4*)v0;
    rb.v = *(const uint4*)(v0 + ldq);
    glds16(kp0, &Klds[0][(w * 8) * 128]);
    glds16(kp1, &Klds[0][(w * 8 + 4) * 128]);
  }

  for (int kt = 0; kt <= qb; ++kt) {
    const int cur = kt & 1;
    __syncthreads();  // S1: drains K(kt) glds + V(kt) reg loads; prev tile consumed
    {
      // V transpose write: packed pair writes (2 lanes/bank = free)
#pragma unroll
      for (int j = 0; j < 8; ++j) {
        unsigned pk = (unsigned)ra.s[j] | ((unsigned)rb.s[j] << 16);
        *(unsigned*)&Vtlds[(vhb + j) * 72 + vs0] = pk;
      }
    }
    __syncthreads();  // S2: Vt visible (Klds[cur] was already drained at S1)

    if (kt < qb) {  // prefetch next tile: K -> Klds[cur^1], V -> regs
      glds16(kp0 + (size_t)(kt + 1) * 64 * ldq, &Klds[cur ^ 1][(w * 8) * 128]);
      glds16(kp1 + (size_t)(kt + 1) * 64 * ldq, &Klds[cur ^ 1][(w * 8 + 4) * 128]);
      const u16* v0 = Vg + (size_t)(seq0 + (kt + 1) * 64 + vs0) * ldq + vhb;
      ra.v = *(const uint4*)v0;
      rb.v = *(const uint4*)(v0 + ldq);
    }

    // S = Q K^T : 32x64 per wave (2 row-fragments)
    f32x4 sfr[2][4];
#pragma unroll
    for (int rf = 0; rf < 2; ++rf)
#pragma unroll
      for (int c = 0; c < 4; ++c) {
        f32x4 acc = f32x4{0.f, 0.f, 0.f, 0.f};
#pragma unroll
        for (int ks = 0; ks < 4; ++ks) {
          int rr = c * 16 + ln15;
          int ph = (ks * 4 + quad) ^ (rr & 7);
          bf16x8 kf = *(const bf16x8*)&Klds[cur][rr * 128 + ph * 8];
          acc = __builtin_amdgcn_mfma_f32_16x16x32_bf16(qf[rf][ks], kf, acc, 0, 0, 0);
        }
        sfr[rf][c] = acc;
      }

    if (kt == qb) {  // diagonal tile: mask col>row (offsets cancel)
#pragma unroll
      for (int rf = 0; rf < 2; ++rf)
#pragma unroll
        for (int c = 0; c < 4; ++c) {
          int col = c * 16 + ln15;
#pragma unroll
          for (int r = 0; r < 4; ++r)
            if (col > half * 32 + rf * 16 + quad * 4 + r) sfr[rf][c][r] = -INFINITY;
        }
    }

    // online softmax; row (quad*4+r) spans the 16 lanes of a quad
    float mx[2][4];
#pragma unroll
    for (int rf = 0; rf < 2; ++rf)
#pragma unroll
      for (int r = 0; r < 4; ++r) {
        float m0 = fmaxf(fmaxf(sfr[rf][0][r], sfr[rf][1][r]),
                         fmaxf(sfr[rf][2][r], sfr[rf][3][r]));
        m0 = fmaxf(m0, __shfl_xor(m0, 1));
        m0 = fmaxf(m0, __shfl_xor(m0, 2));
        m0 = fmaxf(m0, __shfl_xor(m0, 4));
        m0 = fmaxf(m0, __shfl_xor(m0, 8));
        mx[rf][r] = m0;
      }
    // T13 defer-max: rescale only when some row's max grew by > 8 (P <= e^8)
    float ex = -INFINITY;
#pragma unroll
    for (int rf = 0; rf < 2; ++rf)
#pragma unroll
      for (int r = 0; r < 4; ++r) ex = fmaxf(ex, mx[rf][r] - m_r[rf][r]);
    if (!__all(ex <= 8.f)) {
#pragma unroll
      for (int rf = 0; rf < 2; ++rf)
#pragma unroll
        for (int r = 0; r < 4; ++r) {
          float mnew = fmaxf(m_r[rf][r], mx[rf][r]);
          float al = exp2f((m_r[rf][r] - mnew) * L2E);
          m_r[rf][r] = mnew;
          l_r[rf][r] *= al;
#pragma unroll
          for (int ht = 0; ht < 8; ++ht) o[rf][ht][r] *= al;
        }
    }
#pragma unroll
    for (int rf = 0; rf < 2; ++rf)
#pragma unroll
      for (int r = 0; r < 4; ++r) {
        float rs = 0.f;
#pragma unroll
        for (int c = 0; c < 4; ++c) {
          float pv = exp2f((sfr[rf][c][r] - m_r[rf][r]) * L2E);
          sfr[rf][c][r] = pv;
          rs += pv;
        }
        rs += __shfl_xor(rs, 1);
        rs += __shfl_xor(rs, 2);
        rs += __shfl_xor(rs, 4);
        rs += __shfl_xor(rs, 8);
        l_r[rf][r] += rs;
      }

    // P: C-layout -> LDS -> A-layout (bf16); Plds region is wave-private
#pragma unroll
    for (int rf = 0; rf < 2; ++rf)
#pragma unroll
      for (int c = 0; c < 4; ++c)
#pragma unroll
        for (int r = 0; r < 4; ++r)
          Plds[w * 2304 + (rf * 16 + quad * 4 + r) * 72 + c * 16 + ln15] =
              f2bf(sfr[rf][c][r]);

    asm volatile("s_waitcnt lgkmcnt(0)" ::: "memory");

    bf16x8 pf[2][2];
#pragma unroll
    for (int rf = 0; rf < 2; ++rf)
#pragma unroll
      for (int ks = 0; ks < 2; ++ks)
        pf[rf][ks] =
            *(const bf16x8*)&Plds[w * 2304 + (rf * 16 + ln15) * 72 + ks * 32 + quad * 8];
#pragma unroll
    for (int ht = 0; ht < 8; ++ht)
#pragma unroll
      for (int ks = 0; ks < 2; ++ks) {
        bf16x8 vf = *(const bf16x8*)&Vtlds[(ht * 16 + ln15) * 72 + ks * 32 + quad * 8];
#pragma unroll
        for (int rf = 0; rf < 2; ++rf)
          o[rf][ht] = __builtin_amdgcn_mfma_f32_16x16x32_bf16(pf[rf][ks], vf, o[rf][ht],
                                                              0, 0, 0);
      }
  }

#pragma unroll
  for (int rf = 0; rf < 2; ++rf)
#pragma unroll
    for (int r = 0; r < 4; ++r) l_r[rf][r] = 1.f / l_r[rf][r];
#pragma unroll
  for (int rf = 0; rf < 2; ++rf)
#pragma unroll
    for (int ht = 0; ht < 8; ++ht)
#pragma unroll
      for (int r = 0; r < 4; ++r)
        outp[(size_t)(q0 + half * 32 + rf * 16 + quad * 4 + r) * 4096 + n * 128 +
             ht * 16 + ln15] = f2bf(o[rf][ht][r] * l_r[rf][r]);
}

// ---------------- host ----------------
extern "C" void kernel_launch(void* const* d_in, const int* in_sizes, int n_in,
                              void* d_out, int out_size, void* d_ws, size_t ws_size,
                              hipStream_t stream) {
  const float* x = (const float*)d_in[0];
  const int* posi = (const int*)d_in[1];
  const float* Wq = (const float*)d_in[2];
  const float* Wk = (const float*)d_in[3];
  const float* Wv = (const float*)d_in[4];
  const float* Wo = (const float*)d_in[5];
  float* out = (float*)d_out;
  char* ws = (char*)d_ws;

  // workspace layout (bytes); attn reuses xb region (disjoint lifetimes). 168 MB total.
  u16* xb = (u16*)(ws);                         // [4096][4096] bf16, 33.5 MB
  u16* Wt = (u16*)(ws + 33554432);              // [6144][4096] bf16 (Wq^T|Wk^T|Wv^T), 50.3 MB
  u16* WoT = (u16*)(ws + 83886080);             // [4096][4096] bf16 (Wo^T), 33.5 MB
  u16* qkv = (u16*)(ws + 117440512);            // [4096][6144] bf16, 50.3 MB
  u16* attn = xb;                               // [4096][4096] bf16 (after x consumed)
  float2* rtab = (float2*)ws;                   // 512 KB sincos table; dead window of xb

  cvt_kernel<<<16384, 256, 0, stream>>>((const float4*)x, (uint2*)xb, 4194304);
  tcvt_kernel<<<dim3(128, 128), dim3(32, 8), 0, stream>>>(Wq, Wt, 4096, 4096);
  tcvt_kernel<<<dim3(32, 128), dim3(32, 8), 0, stream>>>(Wk, Wt + (size_t)4096 * 4096, 4096, 1024);
  tcvt_kernel<<<dim3(32, 128), dim3(32, 8), 0, stream>>>(Wv, Wt + (size_t)5120 * 4096, 4096, 1024);
  tcvt_kernel<<<dim3(128, 128), dim3(32, 8), 0, stream>>>(Wo, WoT, 4096, 4096);

  gemm_nt8<1><<<dim3(384), 512, 0, stream>>>(xb, Wt, qkv, 4096, 6144, 4096);
  ropetab_kernel<<<256, 256, 0, stream>>>(rtab);
  rope_kernel<<<40960, 256, 0, stream>>>(qkv, posi, rtab, 10485760);
  attn_kernel<<<512, 512, 0, stream>>>(qkv, attn);
  gemm_nt8<0><<<dim3(256), 512, 0, stream>>>(attn, WoT, out, 4096, 4096, 4096);
}

// Round 5
// 665.926 us; speedup vs baseline: 1.1908x; 1.0325x over previous
//
#include <hip/hip_runtime.h>
#include <cstdint>

// LlamaAttention prefill: x[T,D] -> QKV gemm(+fused RoPE) -> causal GQA flash attn -> O gemm
// T=4096 (B=4 x S=1024), D=4096, N=32 q-heads, K=8 kv-heads, H=128.
// Round 5: RoPE fused into the QKV gemm epilogue via wave-column remap
// (j-frag cols = (wn>>1)*128+(wn&1)*32+(j&1)*16+(j>>1)*64, so rope pairs
// (i,i+64) are thread-local in acc[m][j]/acc[m][j+2]); rope_kernel removed.
// tcvt upgraded to 64x64 float4/ushort4 tiles. Attn unchanged from round 4.

typedef unsigned short u16;
typedef short bf16x8 __attribute__((ext_vector_type(8)));
typedef float f32x4 __attribute__((ext_vector_type(4)));

#define L2E 1.44269504088896340736f

static __device__ __forceinline__ u16 f2bf(float f) {
  union { float f; unsigned u; } v; v.f = f;
  unsigned r = (v.u + 0x7fffu + ((v.u >> 16) & 1u)) >> 16;
  return (u16)r;
}
static __device__ __forceinline__ float bf2f(u16 h) {
  union { unsigned u; float f; } v; v.u = ((unsigned)h) << 16;
  return v.f;
}

typedef __attribute__((address_space(1))) const unsigned int gas_u32;
typedef __attribute__((address_space(3))) unsigned int las_u32;
// async global->LDS, 16B per lane; LDS dest must be wave-uniform base (+lane*16).
static __device__ __forceinline__ void glds16(const void* g, const void* l) {
  __builtin_amdgcn_global_load_lds((gas_u32*)(uintptr_t)g,
                                   (las_u32*)(unsigned)(uintptr_t)l, 16, 0, 0);
}

// ---------------- fp32 -> bf16 elementwise ----------------
__global__ __launch_bounds__(256) void cvt_kernel(const float4* __restrict__ in,
                                                  uint2* __restrict__ out, int n4) {
  int i = blockIdx.x * 256 + threadIdx.x;
  if (i < n4) {
    float4 v = in[i];
    uint2 r;
    r.x = (unsigned)f2bf(v.x) | ((unsigned)f2bf(v.y) << 16);
    r.y = (unsigned)f2bf(v.z) | ((unsigned)f2bf(v.w) << 16);
    out[i] = r;
  }
}

// ---------------- fp32 [R][C] -> bf16 [C][R] tiled transpose (64x64, vectorized) ----
__global__ __launch_bounds__(256) void tcvt_kernel(const float* __restrict__ in,
                                                   u16* __restrict__ out, int R, int C) {
  __shared__ float tile[64][68];  // pad 68: rows 272B (16B-aligned), ~4-way banks
  int tx = threadIdx.x & 15, ty = threadIdx.x >> 4;
  int r0 = blockIdx.y * 64, c0 = blockIdx.x * 64;
#pragma unroll
  for (int k = 0; k < 4; ++k) {
    float4 v = *(const float4*)&in[(size_t)(r0 + ty + k * 16) * C + c0 + tx * 4];
    *(float4*)&tile[ty + k * 16][tx * 4] = v;
  }
  __syncthreads();
#pragma unroll
  for (int k = 0; k < 4; ++k) {
    int ocol = ty + k * 16;
    ushort4 o;
    o.x = f2bf(tile[tx * 4 + 0][ocol]);
    o.y = f2bf(tile[tx * 4 + 1][ocol]);
    o.z = f2bf(tile[tx * 4 + 2][ocol]);
    o.w = f2bf(tile[tx * 4 + 3][ocol]);
    *(ushort4*)&out[(size_t)(c0 + ocol) * R + r0 + tx * 4] = o;
  }
}

// ---------------- RoPE sincos table: tab[p*64+i] = (cos, sin) of p*theta^{-i/64} ----
__global__ __launch_bounds__(256) void ropetab_kernel(float2* __restrict__ tab) {
  int idx = blockIdx.x * 256 + threadIdx.x;  // 65536 = 1024 pos * 64 pairs
  int i = idx & 63;
  float inv = exp2f(-0.20751874963942190927f * (float)i);
  float f = (float)(idx >> 6) * inv;
  float s, c;
  sincosf(f, &s, &c);
  tab[idx] = make_float2(c, s);
}

// ---------------- NT GEMM: C[M,N] = A[M,K] * B[N,K]^T (bf16 in, fp32 acc) --------
// 256x256 tile, BK=64 as two K=32 slabs, 512 thr = 8 waves (2M x 4N), per-wave
// 128x64 output (acc[8][4]). 8-phase counted-vmcnt schedule (stable since r1).
// Wave column map: col(j) = n0 + (wn>>1)*128 + (wn&1)*32 + (j&1)*16 + (j>>1)*64
// + ln15  ->  acc[m][j] / acc[m][j+2] are rope pairs (i, i+64) of one 128-col
// head, enabling the fused RoPE epilogue (ROPE=1: q cols scaled+rotated, k cols
// rotated, v cols passthrough; per 256-col block the category is uniform).
template <int BF16OUT, int ROPE>
__global__ __launch_bounds__(512, 2) void gemm_nt8(const u16* __restrict__ A,
                                                   const u16* __restrict__ Bm,
                                                   void* __restrict__ Cp,
                                                   int M, int N, int Kd,
                                                   const int* __restrict__ posi,
                                                   const float2* __restrict__ rtab) {
  __shared__ u16 Als[2][2][8192];  // [buf][ks][row*32+col], 64 KiB
  __shared__ u16 Bls[2][2][8192];  // 64 KiB
  const int tid = threadIdx.x;
  const int w = tid >> 6, lane = tid & 63;
  const int ln15 = lane & 15, quad = lane >> 4;
  const int wm = w & 1, wn = w >> 1;  // 2 x 4 wave grid

  // XCD-aware swizzle (nwg % 8 == 0 for all our shapes)
  const int nbm = M >> 8;
  const int nwg = nbm * (N >> 8);
  const int cpx = nwg >> 3;
  const int bid = blockIdx.x;
  const int swz = (bid & 7) * cpx + (bid >> 3);
  const int bm = swz & (nbm - 1);
  const int bn = swz / nbm;
  const int m0 = bm << 8, n0 = bn << 8;

  const int nt = Kd >> 6;  // K-tiles (even; K multiple of 128)

  // staging: wave w instr h covers rows w*32+h*16+(lane>>2), chunk lane&3;
  // source chunk pre-swizzled so linear LDS dest yields swizzled layout.
  const int srow = lane >> 2;
  const int schk = ((lane & 3) ^ ((lane >> 3) & 3)) << 3;  // elements
  const u16* aSrc = A + (size_t)(m0 + w * 32 + srow) * Kd + schk;
  const u16* bSrc = Bm + (size_t)(n0 + w * 32 + srow) * Kd + schk;
  const int ldsb = w * 1024;  // element offset of wave's staging rows (w*32 rows)

  // LDS read base addresses: row*32 elems + swizzled chunk; swizzle key
  // ((row mod 16)>>1) is invariant under the multiple-of-16 row offsets.
  const int rswz = (quad ^ ((ln15 >> 1) & 3)) << 3;
  const int aoff = (wm * 128 + ln15) * 32 + rswz;
  const int boff = ((wn >> 1) * 128 + (wn & 1) * 32 + ln15) * 32 + rswz;
  const unsigned aAddr = (unsigned)(uintptr_t)&Als[0][0][aoff];
  const unsigned bAddr = (unsigned)(uintptr_t)&Bls[0][0][boff];

  f32x4 acc[8][4];
#pragma unroll
  for (int i = 0; i < 8; ++i)
#pragma unroll
    for (int j = 0; j < 4; ++j) acc[i][j] = f32x4{0.f, 0.f, 0.f, 0.f};
  bf16x8 af[8];

#define DSR(dst, addr, off) \
  asm volatile("ds_read_b128 %0, %1 offset:%2" : "=v"(dst) : "v"(addr), "i"(off))

#define STA(kt, buf, ks)                                          \
  do {                                                            \
    int kc_ = (kt) < nt ? (kt) : nt - 1;                          \
    const u16* s_ = aSrc + (size_t)kc_ * 64 + (ks) * 32;          \
    glds16(s_, &Als[buf][ks][ldsb]);                              \
    glds16(s_ + (size_t)16 * Kd, &Als[buf][ks][ldsb + 512]);      \
  } while (0)
#define STB(kt, buf, ks)                                          \
  do {                                                            \
    int kc_ = (kt) < nt ? (kt) : nt - 1;                          \
    const u16* s_ = bSrc + (size_t)kc_ * 64 + (ks) * 32;          \
    glds16(s_, &Bls[buf][ks][ldsb]);                              \
    glds16(s_ + (size_t)16 * Kd, &Bls[buf][ks][ldsb + 512]);      \
  } while (0)

  // b-frag (nh, s): rows (nh*64 + s*16) from boff base -> bytes nh*4096 + s*1024
#define PHASE(buf, ks, nh, STAGE, VM)                                              \
  do {                                                                             \
    if ((nh) == 0) {                                                               \
      DSR(af[0], aAddr, (buf)*32768 + (ks)*16384 + 0 * 1024);                      \
      DSR(af[1], aAddr, (buf)*32768 + (ks)*16384 + 1 * 1024);                      \
      DSR(af[2], aAddr, (buf)*32768 + (ks)*16384 + 2 * 1024);                      \
      DSR(af[3], aAddr, (buf)*32768 + (ks)*16384 + 3 * 1024);                      \
      DSR(af[4], aAddr, (buf)*32768 + (ks)*16384 + 4 * 1024);                      \
      DSR(af[5], aAddr, (buf)*32768 + (ks)*16384 + 5 * 1024);                      \
      DSR(af[6], aAddr, (buf)*32768 + (ks)*16384 + 6 * 1024);                      \
      DSR(af[7], aAddr, (buf)*32768 + (ks)*16384 + 7 * 1024);                      \
    }                                                                              \
    bf16x8 b0_, b1_;                                                               \
    DSR(b0_, bAddr, (buf)*32768 + (ks)*16384 + (nh)*4096);                         \
    DSR(b1_, bAddr, (buf)*32768 + (ks)*16384 + (nh)*4096 + 1024);                  \
    STAGE;                                                                         \
    __builtin_amdgcn_s_barrier();                                                  \
    asm volatile("s_waitcnt lgkmcnt(0)" ::: "memory");                             \
    __builtin_amdgcn_sched_barrier(0);                                             \
    __builtin_amdgcn_s_setprio(1);                                                 \
    _Pragma("unroll") for (int m_ = 0; m_ < 8; ++m_) {                             \
      acc[m_][2 * (nh)] =                                                          \
          __builtin_amdgcn_mfma_f32_16x16x32_bf16(af[m_], b0_, acc[m_][2 * (nh)],  \
                                                  0, 0, 0);                        \
      acc[m_][2 * (nh) + 1] = __builtin_amdgcn_mfma_f32_16x16x32_bf16(             \
          af[m_], b1_, acc[m_][2 * (nh) + 1], 0, 0, 0);                            \
    }                                                                              \
    __builtin_amdgcn_s_setprio(0);                                                 \
    if (VM) asm volatile("s_waitcnt vmcnt(6)" ::: "memory");                       \
    __builtin_amdgcn_s_barrier();                                                  \
    __builtin_amdgcn_sched_barrier(0);                                             \
  } while (0)

  // prologue: tile0 fully + 3 half-tiles of tile1; vmcnt(6) drains tile0.
  STA(0, 0, 0); STB(0, 0, 0); STA(0, 0, 1); STB(0, 0, 1);
  STA(1, 1, 0); STB(1, 1, 0); STA(1, 1, 1);
  asm volatile("s_waitcnt vmcnt(6)" ::: "memory");
  __builtin_amdgcn_s_barrier();
  __builtin_amdgcn_sched_barrier(0);

  const int iters = nt >> 1;
  for (int i = 0; i < iters; ++i) {
    const int t = 2 * i;
    PHASE(0, 0, 0, STB(t + 1, 1, 1), 0);
    PHASE(0, 0, 1, STA(t + 2, 0, 0), 0);
    PHASE(0, 1, 0, STB(t + 2, 0, 0), 0);
    PHASE(0, 1, 1, STA(t + 2, 0, 1), 1);
    PHASE(1, 0, 0, STB(t + 2, 0, 1), 0);
    PHASE(1, 0, 1, STA(t + 3, 1, 0), 0);
    PHASE(1, 1, 0, STB(t + 3, 1, 0), 0);
    PHASE(1, 1, 1, STA(t + 3, 1, 1), 1);
  }
#undef PHASE
#undef STA
#undef STB
#undef DSR

  // epilogue: C-write. col(j) = ccol + (j&1)*16 + (j>>1)*64.
  const int crow = m0 + wm * 128 + quad * 4;
  const int ccol = n0 + (wn >> 1) * 128 + (wn & 1) * 32 + ln15;
  const int cat = (n0 < 4096) ? 0 : (n0 < 5120 ? 1 : 2);  // q / k / v

  if (ROPE && cat < 2) {
    const float qs = (cat == 0) ? 0.08838834764831845f : 1.0f;
    const int i0 = (wn & 1) * 32 + ln15;  // rope pair index for s=0
#pragma unroll
    for (int m = 0; m < 8; ++m)
#pragma unroll
      for (int r = 0; r < 4; ++r) {
        int row = crow + m * 16 + r;
        int p = posi[row];
#pragma unroll
        for (int s = 0; s < 2; ++s) {
          float2 cs = rtab[(p << 6) + i0 + s * 16];
          float x1 = acc[m][s][r], x2 = acc[m][s + 2][r];
          float o1 = (x1 * cs.x - x2 * cs.y) * qs;
          float o2 = (x2 * cs.x + x1 * cs.y) * qs;
          ((u16*)Cp)[(size_t)row * N + ccol + s * 16] = f2bf(o1);
          ((u16*)Cp)[(size_t)row * N + ccol + s * 16 + 64] = f2bf(o2);
        }
      }
  } else {
#pragma unroll
    for (int m = 0; m < 8; ++m)
#pragma unroll
      for (int j = 0; j < 4; ++j) {
        int col = ccol + (j & 1) * 16 + (j >> 1) * 64;
#pragma unroll
        for (int r = 0; r < 4; ++r) {
          float v = acc[m][j][r];
          if (BF16OUT)
            ((u16*)Cp)[(size_t)(crow + m * 16 + r) * N + col] = f2bf(v);
          else
            ((float*)Cp)[(size_t)(crow + m * 16 + r) * N + col] = v;
        }
      }
  }
}

// ---------------- Flash attention, causal, GQA-grouped ----------------
// grid = 512 = 16 qb-tiles x 8 kv-heads x 4 seqs, globally qb-descending.
// Block = 512 thr = 8 waves = one full GQA group (4 q-heads x 64 q-rows);
// wave w: head w&3, row-half w>>2 (32 rows = 2 fragments of 16).
// K [2][64][128] LDS double-buffer, staged once per tile for all 4 heads via
// swizzled glds; K(kt+1) prefetch issued after S2 (latency hides under compute,
// next S1's vmcnt(0) is the covering wait). V reg-prefetch (T14) -> transposed
// [128][72] LDS write. Online softmax with defer-max (T13). P->LDS per wave.
__global__ __launch_bounds__(512, 2) void attn_kernel(const u16* __restrict__ qkv,
                                                      u16* __restrict__ outp) {
  __shared__ u16 Klds[2][64 * 128];   // 32 KB
  __shared__ u16 Vtlds[128 * 72];     // 18 KB
  __shared__ u16 Plds[8 * 32 * 72];   // 36 KB (per-wave 32 rows)

  const int bx = blockIdx.x;
  const int qb = 15 - (bx >> 5);      // global heavy-first ordering
  const int kh = bx & 7;
  const int b = (bx >> 3) & 3;

  const int tid = threadIdx.x;
  const int w = tid >> 6;             // 0..7
  const int lane = tid & 63;
  const int ln15 = lane & 15;
  const int quad = lane >> 4;
  const int g = w & 3;                // q-head within group
  const int half = w >> 2;            // row half (0/1)
  const int n = kh * 4 + g;

  const int ldq = 6144;
  const int seq0 = b << 10;
  const int q0 = seq0 + qb * 64;

  const u16* Qg = qkv + n * 128;
  const u16* Kg = qkv + 4096 + kh * 128;
  const u16* Vg = qkv + 5120 + kh * 128;

  // Q fragments: rf in {0,1}; A-layout row m=ln15, k=quad*8+j (q pre-scaled in rope)
  bf16x8 qf[2][4];
#pragma unroll
  for (int rf = 0; rf < 2; ++rf) {
    const u16* qrow = Qg + (size_t)(q0 + half * 32 + rf * 16 + ln15) * ldq + quad * 8;
#pragma unroll
    for (int ks = 0; ks < 4; ++ks) qf[rf][ks] = *(const bf16x8*)(qrow + ks * 32);
  }

  f32x4 o[2][8];
#pragma unroll
  for (int rf = 0; rf < 2; ++rf)
#pragma unroll
    for (int i = 0; i < 8; ++i) o[rf][i] = f32x4{0.f, 0.f, 0.f, 0.f};
  float m_r[2][4], l_r[2][4];
#pragma unroll
  for (int rf = 0; rf < 2; ++rf)
#pragma unroll
    for (int r = 0; r < 4; ++r) { m_r[rf][r] = -INFINITY; l_r[rf][r] = 0.f; }

  // K staging: wave w covers rows w*8 + q*4 + (lane>>4), q in {0,1}; chunk-XOR
  // pre-swizzle on the global source so the linear glds dest is swizzled.
  const int kr0 = w * 8 + (lane >> 4);
  const int kr1 = kr0 + 4;
  const u16* kp0 = Kg + (size_t)(seq0 + kr0) * ldq + (((lane & 15) ^ (kr0 & 7)) << 3);
  const u16* kp1 = Kg + (size_t)(seq0 + kr1) * ldq + (((lane & 15) ^ (kr1 & 7)) << 3);

  // V staging: thread covers rows (vs0, vs0+1) x 8 h-cols starting at vhb
  const int vs0 = (tid & 31) * 2;
  const int vhb = (tid >> 5) * 8;

  union V8 { uint4 v; u16 s[8]; };
  V8 ra, rb;
  {  // prefetch V tile 0 + stage K tile 0
    const u16* v0 = Vg + (size_t)(seq0 + vs0) * ldq + vhb;
    ra.v = *(const uint4*)v0;
    rb.v = *(const uint4*)(v0 + ldq);
    glds16(kp0, &Klds[0][(w * 8) * 128]);
    glds16(kp1, &Klds[0][(w * 8 + 4) * 128]);
  }

  for (int kt = 0; kt <= qb; ++kt) {
    const int cur = kt & 1;
    __syncthreads();  // S1: drains K(kt) glds + V(kt) reg loads; prev tile consumed
    {
      // V transpose write: packed pair writes (2 lanes/bank = free)
#pragma unroll
      for (int j = 0; j < 8; ++j) {
        unsigned pk = (unsigned)ra.s[j] | ((unsigned)rb.s[j] << 16);
        *(unsigned*)&Vtlds[(vhb + j) * 72 + vs0] = pk;
      }
    }
    __syncthreads();  // S2: Vt visible (Klds[cur] was already drained at S1)

    if (kt < qb) {  // prefetch next tile: K -> Klds[cur^1], V -> regs
      glds16(kp0 + (size_t)(kt + 1) * 64 * ldq, &Klds[cur ^ 1][(w * 8) * 128]);
      glds16(kp1 + (size_t)(kt + 1) * 64 * ldq, &Klds[cur ^ 1][(w * 8 + 4) * 128]);
      const u16* v0 = Vg + (size_t)(seq0 + (kt + 1) * 64 + vs0) * ldq + vhb;
      ra.v = *(const uint4*)v0;
      rb.v = *(const uint4*)(v0 + ldq);
    }

    // S = Q K^T : 32x64 per wave (2 row-fragments)
    f32x4 sfr[2][4];
#pragma unroll
    for (int rf = 0; rf < 2; ++rf)
#pragma unroll
      for (int c = 0; c < 4; ++c) {
        f32x4 acc = f32x4{0.f, 0.f, 0.f, 0.f};
#pragma unroll
        for (int ks = 0; ks < 4; ++ks) {
          int rr = c * 16 + ln15;
          int ph = (ks * 4 + quad) ^ (rr & 7);
          bf16x8 kf = *(const bf16x8*)&Klds[cur][rr * 128 + ph * 8];
          acc = __builtin_amdgcn_mfma_f32_16x16x32_bf16(qf[rf][ks], kf, acc, 0, 0, 0);
        }
        sfr[rf][c] = acc;
      }

    if (kt == qb) {  // diagonal tile: mask col>row (offsets cancel)
#pragma unroll
      for (int rf = 0; rf < 2; ++rf)
#pragma unroll
        for (int c = 0; c < 4; ++c) {
          int col = c * 16 + ln15;
#pragma unroll
          for (int r = 0; r < 4; ++r)
            if (col > half * 32 + rf * 16 + quad * 4 + r) sfr[rf][c][r] = -INFINITY;
        }
    }

    // online softmax; row (quad*4+r) spans the 16 lanes of a quad
    float mx[2][4];
#pragma unroll
    for (int rf = 0; rf < 2; ++rf)
#pragma unroll
      for (int r = 0; r < 4; ++r) {
        float m0 = fmaxf(fmaxf(sfr[rf][0][r], sfr[rf][1][r]),
                         fmaxf(sfr[rf][2][r], sfr[rf][3][r]));
        m0 = fmaxf(m0, __shfl_xor(m0, 1));
        m0 = fmaxf(m0, __shfl_xor(m0, 2));
        m0 = fmaxf(m0, __shfl_xor(m0, 4));
        m0 = fmaxf(m0, __shfl_xor(m0, 8));
        mx[rf][r] = m0;
      }
    // T13 defer-max: rescale only when some row's max grew by > 8 (P <= e^8)
    float ex = -INFINITY;
#pragma unroll
    for (int rf = 0; rf < 2; ++rf)
#pragma unroll
      for (int r = 0; r < 4; ++r) ex = fmaxf(ex, mx[rf][r] - m_r[rf][r]);
    if (!__all(ex <= 8.f)) {
#pragma unroll
      for (int rf = 0; rf < 2; ++rf)
#pragma unroll
        for (int r = 0; r < 4; ++r) {
          float mnew = fmaxf(m_r[rf][r], mx[rf][r]);
          float al = exp2f((m_r[rf][r] - mnew) * L2E);
          m_r[rf][r] = mnew;
          l_r[rf][r] *= al;
#pragma unroll
          for (int ht = 0; ht < 8; ++ht) o[rf][ht][r] *= al;
        }
    }
#pragma unroll
    for (int rf = 0; rf < 2; ++rf)
#pragma unroll
      for (int r = 0; r < 4; ++r) {
        float rs = 0.f;
#pragma unroll
        for (int c = 0; c < 4; ++c) {
          float pv = exp2f((sfr[rf][c][r] - m_r[rf][r]) * L2E);
          sfr[rf][c][r] = pv;
          rs += pv;
        }
        rs += __shfl_xor(rs, 1);
        rs += __shfl_xor(rs, 2);
        rs += __shfl_xor(rs, 4);
        rs += __shfl_xor(rs, 8);
        l_r[rf][r] += rs;
      }

    // P: C-layout -> LDS -> A-layout (bf16); Plds region is wave-private
#pragma unroll
    for (int rf = 0; rf < 2; ++rf)
#pragma unroll
      for (int c = 0; c < 4; ++c)
#pragma unroll
        for (int r = 0; r < 4; ++r)
          Plds[w * 2304 + (rf * 16 + quad * 4 + r) * 72 + c * 16 + ln15] =
              f2bf(sfr[rf][c][r]);

    asm volatile("s_waitcnt lgkmcnt(0)" ::: "memory");

    bf16x8 pf[2][2];
#pragma unroll
    for (int rf = 0; rf < 2; ++rf)
#pragma unroll
      for (int ks = 0; ks < 2; ++ks)
        pf[rf][ks] =
            *(const bf16x8*)&Plds[w * 2304 + (rf * 16 + ln15) * 72 + ks * 32 + quad * 8];
#pragma unroll
    for (int ht = 0; ht < 8; ++ht)
#pragma unroll
      for (int ks = 0; ks < 2; ++ks) {
        bf16x8 vf = *(const bf16x8*)&Vtlds[(ht * 16 + ln15) * 72 + ks * 32 + quad * 8];
#pragma unroll
        for (int rf = 0; rf < 2; ++rf)
          o[rf][ht] = __builtin_amdgcn_mfma_f32_16x16x32_bf16(pf[rf][ks], vf, o[rf][ht],
                                                              0, 0, 0);
      }
  }

#pragma unroll
  for (int rf = 0; rf < 2; ++rf)
#pragma unroll
    for (int r = 0; r < 4; ++r) l_r[rf][r] = 1.f / l_r[rf][r];
#pragma unroll
  for (int rf = 0; rf < 2; ++rf)
#pragma unroll
    for (int ht = 0; ht < 8; ++ht)
#pragma unroll
      for (int r = 0; r < 4; ++r)
        outp[(size_t)(q0 + half * 32 + rf * 16 + quad * 4 + r) * 4096 + n * 128 +
             ht * 16 + ln15] = f2bf(o[rf][ht][r] * l_r[rf][r]);
}

// ---------------- host ----------------
extern "C" void kernel_launch(void* const* d_in, const int* in_sizes, int n_in,
                              void* d_out, int out_size, void* d_ws, size_t ws_size,
                              hipStream_t stream) {
  const float* x = (const float*)d_in[0];
  const int* posi = (const int*)d_in[1];
  const float* Wq = (const float*)d_in[2];
  const float* Wk = (const float*)d_in[3];
  const float* Wv = (const float*)d_in[4];
  const float* Wo = (const float*)d_in[5];
  float* out = (float*)d_out;
  char* ws = (char*)d_ws;

  // workspace layout (bytes); attn reuses xb region (disjoint lifetimes).
  u16* xb = (u16*)(ws);                         // [4096][4096] bf16, 33.5 MB
  u16* Wt = (u16*)(ws + 33554432);              // [6144][4096] bf16 (Wq^T|Wk^T|Wv^T), 50.3 MB
  u16* WoT = (u16*)(ws + 83886080);             // [4096][4096] bf16 (Wo^T), 33.5 MB
  u16* qkv = (u16*)(ws + 117440512);            // [4096][6144] bf16, 50.3 MB
  u16* attn = xb;                               // [4096][4096] bf16 (after x consumed)
  float2* rtab = (float2*)d_out;                // 512 KB sincos table in d_out (dead
                                                // until the final O-proj overwrites it)

  cvt_kernel<<<16384, 256, 0, stream>>>((const float4*)x, (uint2*)xb, 4194304);
  tcvt_kernel<<<dim3(64, 64), 256, 0, stream>>>(Wq, Wt, 4096, 4096);
  tcvt_kernel<<<dim3(16, 64), 256, 0, stream>>>(Wk, Wt + (size_t)4096 * 4096, 4096, 1024);
  tcvt_kernel<<<dim3(16, 64), 256, 0, stream>>>(Wv, Wt + (size_t)5120 * 4096, 4096, 1024);
  tcvt_kernel<<<dim3(64, 64), 256, 0, stream>>>(Wo, WoT, 4096, 4096);
  ropetab_kernel<<<256, 256, 0, stream>>>(rtab);

  gemm_nt8<1, 1><<<dim3(384), 512, 0, stream>>>(xb, Wt, qkv, 4096, 6144, 4096, posi, rtab);
  attn_kernel<<<512, 512, 0, stream>>>(qkv, attn);
  gemm_nt8<0, 0><<<dim3(256), 512, 0, stream>>>(attn, WoT, out, 4096, 4096, 4096,
                                                nullptr, nullptr);
}

// Round 8
// 644.847 us; speedup vs baseline: 1.2297x; 1.0327x over previous
//
#include <hip/hip_runtime.h>
#include <cstdint>

// LlamaAttention prefill: x[T,D] -> QKV gemm(+fused RoPE) -> causal GQA flash attn -> O gemm
// T=4096 (B=4 x S=1024), D=4096, N=32 q-heads, K=8 kv-heads, H=128.
// Round 8 (2nd resubmit of round 6; infra timeouts): attn restructure — delayed-PV
// (PV(kt-1) fused behind QK(kt) into one 64-MFMA setprio cluster), single barrier
// per tile (S2 removed; ledger-checked), per-lane l-partials with one end-of-block
// reduce. Prep kernels merged into one dispatch. GEMMs unchanged from round 5.

typedef unsigned short u16;
typedef short bf16x8 __attribute__((ext_vector_type(8)));
typedef float f32x4 __attribute__((ext_vector_type(4)));

#define L2E 1.44269504088896340736f

static __device__ __forceinline__ u16 f2bf(float f) {
  union { float f; unsigned u; } v; v.f = f;
  unsigned r = (v.u + 0x7fffu + ((v.u >> 16) & 1u)) >> 16;
  return (u16)r;
}
static __device__ __forceinline__ float bf2f(u16 h) {
  union { unsigned u; float f; } v; v.u = ((unsigned)h) << 16;
  return v.f;
}

typedef __attribute__((address_space(1))) const unsigned int gas_u32;
typedef __attribute__((address_space(3))) unsigned int las_u32;
// async global->LDS, 16B per lane; LDS dest must be wave-uniform base (+lane*16).
static __device__ __forceinline__ void glds16(const void* g, const void* l) {
  __builtin_amdgcn_global_load_lds((gas_u32*)(uintptr_t)g,
                                   (las_u32*)(unsigned)(uintptr_t)l, 16, 0, 0);
}

// ---------------- fp32 -> bf16 elementwise ----------------
__global__ __launch_bounds__(256) void cvt_kernel(const float4* __restrict__ in,
                                                  uint2* __restrict__ out, int n4) {
  int i = blockIdx.x * 256 + threadIdx.x;
  if (i < n4) {
    float4 v = in[i];
    uint2 r;
    r.x = (unsigned)f2bf(v.x) | ((unsigned)f2bf(v.y) << 16);
    r.y = (unsigned)f2bf(v.z) | ((unsigned)f2bf(v.w) << 16);
    out[i] = r;
  }
}

// ---------------- merged prep: 4x weight transpose-cvt + rope sincos table ------
// blocks [0,4096): Wq->Wt; [4096,5120): Wk; [5120,6144): Wv; [6144,10240): Wo->WoT;
// [10240,10496): rtab. All transposes are 64x64 fp32->bf16 tiles, R=4096 rows.
__global__ __launch_bounds__(256) void prep_kernel(const float* __restrict__ Wq,
                                                   const float* __restrict__ Wk,
                                                   const float* __restrict__ Wv,
                                                   const float* __restrict__ Wo,
                                                   u16* __restrict__ Wt,
                                                   u16* __restrict__ WoT,
                                                   float2* __restrict__ rtab) {
  const int bx = blockIdx.x;
  if (bx >= 10240) {  // rope table: tab[p*64+i] = (cos, sin) of p*theta^{-i/64}
    int idx = (bx - 10240) * 256 + threadIdx.x;
    int i = idx & 63;
    float inv = exp2f(-0.20751874963942190927f * (float)i);
    float f = (float)(idx >> 6) * inv;
    float s, c;
    sincosf(f, &s, &c);
    rtab[idx] = make_float2(c, s);
    return;
  }
  const float* in;
  u16* out;
  int C, t;
  if (bx < 4096)      { in = Wq; out = Wt;                        C = 4096; t = bx; }
  else if (bx < 5120) { in = Wk; out = Wt + (size_t)4096 * 4096;  C = 1024; t = bx - 4096; }
  else if (bx < 6144) { in = Wv; out = Wt + (size_t)5120 * 4096;  C = 1024; t = bx - 5120; }
  else                { in = Wo; out = WoT;                       C = 4096; t = bx - 6144; }
  const int ctiles = C >> 6;
  const int c0 = (t % ctiles) * 64, r0 = (t / ctiles) * 64;

  __shared__ float tile[64][68];  // pad 68: rows 272B (16B-aligned), ~4-way banks
  int tx = threadIdx.x & 15, ty = threadIdx.x >> 4;
#pragma unroll
  for (int k = 0; k < 4; ++k) {
    float4 v = *(const float4*)&in[(size_t)(r0 + ty + k * 16) * C + c0 + tx * 4];
    *(float4*)&tile[ty + k * 16][tx * 4] = v;
  }
  __syncthreads();
#pragma unroll
  for (int k = 0; k < 4; ++k) {
    int ocol = ty + k * 16;
    ushort4 o;
    o.x = f2bf(tile[tx * 4 + 0][ocol]);
    o.y = f2bf(tile[tx * 4 + 1][ocol]);
    o.z = f2bf(tile[tx * 4 + 2][ocol]);
    o.w = f2bf(tile[tx * 4 + 3][ocol]);
    *(ushort4*)&out[(size_t)(c0 + ocol) * 4096 + r0 + tx * 4] = o;
  }
}

// ---------------- NT GEMM: C[M,N] = A[M,K] * B[N,K]^T (bf16 in, fp32 acc) --------
// 256x256 tile, BK=64 as two K=32 slabs, 512 thr = 8 waves (2M x 4N), per-wave
// 128x64 output (acc[8][4]). 8-phase counted-vmcnt schedule (stable since r1).
// Wave column map: col(j) = n0 + (wn>>1)*128 + (wn&1)*32 + (j&1)*16 + (j>>1)*64
// + ln15  ->  acc[m][j] / acc[m][j+2] are rope pairs (i, i+64) of one 128-col
// head, enabling the fused RoPE epilogue (ROPE=1: q cols scaled+rotated, k cols
// rotated, v cols passthrough; per 256-col block the category is uniform).
template <int BF16OUT, int ROPE>
__global__ __launch_bounds__(512, 2) void gemm_nt8(const u16* __restrict__ A,
                                                   const u16* __restrict__ Bm,
                                                   void* __restrict__ Cp,
                                                   int M, int N, int Kd,
                                                   const int* __restrict__ posi,
                                                   const float2* __restrict__ rtab) {
  __shared__ u16 Als[2][2][8192];  // [buf][ks][row*32+col], 64 KiB
  __shared__ u16 Bls[2][2][8192];  // 64 KiB
  const int tid = threadIdx.x;
  const int w = tid >> 6, lane = tid & 63;
  const int ln15 = lane & 15, quad = lane >> 4;
  const int wm = w & 1, wn = w >> 1;  // 2 x 4 wave grid

  // XCD-aware swizzle (nwg % 8 == 0 for all our shapes)
  const int nbm = M >> 8;
  const int nwg = nbm * (N >> 8);
  const int cpx = nwg >> 3;
  const int bid = blockIdx.x;
  const int swz = (bid & 7) * cpx + (bid >> 3);
  const int bm = swz & (nbm - 1);
  const int bn = swz / nbm;
  const int m0 = bm << 8, n0 = bn << 8;

  const int nt = Kd >> 6;  // K-tiles (even; K multiple of 128)

  // staging: wave w instr h covers rows w*32+h*16+(lane>>2), chunk lane&3;
  // source chunk pre-swizzled so linear LDS dest yields swizzled layout.
  const int srow = lane >> 2;
  const int schk = ((lane & 3) ^ ((lane >> 3) & 3)) << 3;  // elements
  const u16* aSrc = A + (size_t)(m0 + w * 32 + srow) * Kd + schk;
  const u16* bSrc = Bm + (size_t)(n0 + w * 32 + srow) * Kd + schk;
  const int ldsb = w * 1024;  // element offset of wave's staging rows (w*32 rows)

  // LDS read base addresses: row*32 elems + swizzled chunk; swizzle key
  // ((row mod 16)>>1) is invariant under the multiple-of-16 row offsets.
  const int rswz = (quad ^ ((ln15 >> 1) & 3)) << 3;
  const int aoff = (wm * 128 + ln15) * 32 + rswz;
  const int boff = ((wn >> 1) * 128 + (wn & 1) * 32 + ln15) * 32 + rswz;
  const unsigned aAddr = (unsigned)(uintptr_t)&Als[0][0][aoff];
  const unsigned bAddr = (unsigned)(uintptr_t)&Bls[0][0][boff];

  f32x4 acc[8][4];
#pragma unroll
  for (int i = 0; i < 8; ++i)
#pragma unroll
    for (int j = 0; j < 4; ++j) acc[i][j] = f32x4{0.f, 0.f, 0.f, 0.f};
  bf16x8 af[8];

#define DSR(dst, addr, off) \
  asm volatile("ds_read_b128 %0, %1 offset:%2" : "=v"(dst) : "v"(addr), "i"(off))

#define STA(kt, buf, ks)                                          \
  do {                                                            \
    int kc_ = (kt) < nt ? (kt) : nt - 1;                          \
    const u16* s_ = aSrc + (size_t)kc_ * 64 + (ks) * 32;          \
    glds16(s_, &Als[buf][ks][ldsb]);                              \
    glds16(s_ + (size_t)16 * Kd, &Als[buf][ks][ldsb + 512]);      \
  } while (0)
#define STB(kt, buf, ks)                                          \
  do {                                                            \
    int kc_ = (kt) < nt ? (kt) : nt - 1;                          \
    const u16* s_ = bSrc + (size_t)kc_ * 64 + (ks) * 32;          \
    glds16(s_, &Bls[buf][ks][ldsb]);                              \
    glds16(s_ + (size_t)16 * Kd, &Bls[buf][ks][ldsb + 512]);      \
  } while (0)

  // b-frag (nh, s): rows (nh*64 + s*16) from boff base -> bytes nh*4096 + s*1024
#define PHASE(buf, ks, nh, STAGE, VM)                                              \
  do {                                                                             \
    if ((nh) == 0) {                                                               \
      DSR(af[0], aAddr, (buf)*32768 + (ks)*16384 + 0 * 1024);                      \
      DSR(af[1], aAddr, (buf)*32768 + (ks)*16384 + 1 * 1024);                      \
      DSR(af[2], aAddr, (buf)*32768 + (ks)*16384 + 2 * 1024);                      \
      DSR(af[3], aAddr, (buf)*32768 + (ks)*16384 + 3 * 1024);                      \
      DSR(af[4], aAddr, (buf)*32768 + (ks)*16384 + 4 * 1024);                      \
      DSR(af[5], aAddr, (buf)*32768 + (ks)*16384 + 5 * 1024);                      \
      DSR(af[6], aAddr, (buf)*32768 + (ks)*16384 + 6 * 1024);                      \
      DSR(af[7], aAddr, (buf)*32768 + (ks)*16384 + 7 * 1024);                      \
    }                                                                              \
    bf16x8 b0_, b1_;                                                               \
    DSR(b0_, bAddr, (buf)*32768 + (ks)*16384 + (nh)*4096);                         \
    DSR(b1_, bAddr, (buf)*32768 + (ks)*16384 + (nh)*4096 + 1024);                  \
    STAGE;                                                                         \
    __builtin_amdgcn_s_barrier();                                                  \
    asm volatile("s_waitcnt lgkmcnt(0)" ::: "memory");                             \
    __builtin_amdgcn_sched_barrier(0);                                             \
    __builtin_amdgcn_s_setprio(1);                                                 \
    _Pragma("unroll") for (int m_ = 0; m_ < 8; ++m_) {                             \
      acc[m_][2 * (nh)] =                                                          \
          __builtin_amdgcn_mfma_f32_16x16x32_bf16(af[m_], b0_, acc[m_][2 * (nh)],  \
                                                  0, 0, 0);                        \
      acc[m_][2 * (nh) + 1] = __builtin_amdgcn_mfma_f32_16x16x32_bf16(             \
          af[m_], b1_, acc[m_][2 * (nh) + 1], 0, 0, 0);                            \
    }                                                                              \
    __builtin_amdgcn_s_setprio(0);                                                 \
    if (VM) asm volatile("s_waitcnt vmcnt(6)" ::: "memory");                       \
    __builtin_amdgcn_s_barrier();                                                  \
    __builtin_amdgcn_sched_barrier(0);                                             \
  } while (0)

  // prologue: tile0 fully + 3 half-tiles of tile1; vmcnt(6) drains tile0.
  STA(0, 0, 0); STB(0, 0, 0); STA(0, 0, 1); STB(0, 0, 1);
  STA(1, 1, 0); STB(1, 1, 0); STA(1, 1, 1);
  asm volatile("s_waitcnt vmcnt(6)" ::: "memory");
  __builtin_amdgcn_s_barrier();
  __builtin_amdgcn_sched_barrier(0);

  const int iters = nt >> 1;
  for (int i = 0; i < iters; ++i) {
    const int t = 2 * i;
    PHASE(0, 0, 0, STB(t + 1, 1, 1), 0);
    PHASE(0, 0, 1, STA(t + 2, 0, 0), 0);
    PHASE(0, 1, 0, STB(t + 2, 0, 0), 0);
    PHASE(0, 1, 1, STA(t + 2, 0, 1), 1);
    PHASE(1, 0, 0, STB(t + 2, 0, 1), 0);
    PHASE(1, 0, 1, STA(t + 3, 1, 0), 0);
    PHASE(1, 1, 0, STB(t + 3, 1, 0), 0);
    PHASE(1, 1, 1, STA(t + 3, 1, 1), 1);
  }
#undef PHASE
#undef STA
#undef STB
#undef DSR

  // epilogue: C-write. col(j) = ccol + (j&1)*16 + (j>>1)*64.
  const int crow = m0 + wm * 128 + quad * 4;
  const int ccol = n0 + (wn >> 1) * 128 + (wn & 1) * 32 + ln15;
  const int cat = (n0 < 4096) ? 0 : (n0 < 5120 ? 1 : 2);  // q / k / v

  if (ROPE && cat < 2) {
    const float qs = (cat == 0) ? 0.08838834764831845f : 1.0f;
    const int i0 = (wn & 1) * 32 + ln15;  // rope pair index for s=0
#pragma unroll
    for (int m = 0; m < 8; ++m)
#pragma unroll
      for (int r = 0; r < 4; ++r) {
        int row = crow + m * 16 + r;
        int p = posi[row];
#pragma unroll
        for (int s = 0; s < 2; ++s) {
          float2 cs = rtab[(p << 6) + i0 + s * 16];
          float x1 = acc[m][s][r], x2 = acc[m][s + 2][r];
          float o1 = (x1 * cs.x - x2 * cs.y) * qs;
          float o2 = (x2 * cs.x + x1 * cs.y) * qs;
          ((u16*)Cp)[(size_t)row * N + ccol + s * 16] = f2bf(o1);
          ((u16*)Cp)[(size_t)row * N + ccol + s * 16 + 64] = f2bf(o2);
        }
      }
  } else {
#pragma unroll
    for (int m = 0; m < 8; ++m)
#pragma unroll
      for (int j = 0; j < 4; ++j) {
        int col = ccol + (j & 1) * 16 + (j >> 1) * 64;
#pragma unroll
        for (int r = 0; r < 4; ++r) {
          float v = acc[m][j][r];
          if (BF16OUT)
            ((u16*)Cp)[(size_t)(crow + m * 16 + r) * N + col] = f2bf(v);
          else
            ((float*)Cp)[(size_t)(crow + m * 16 + r) * N + col] = v;
        }
      }
  }
}

// ---------------- Flash attention, causal, GQA-grouped, delayed-PV --------------
// grid = 512 = 16 qb-tiles x 8 kv-heads x 4 seqs, globally qb-descending.
// Block = 512 thr = 8 waves = one full GQA group (4 q-heads x 64 q-rows);
// wave w: head w&3, row-half w>>2 (32 rows = 2 fragments of 16).
// ONE barrier per K-tile. Per iteration kt:
//   S1 (drains K(kt) glds + V(kt) reg loads; fences all cross-buffer WAR/RAW)
//   V-write(kt)->Vt[c]; issue K(kt+1) glds -> Klds[c^1]; V(kt+1) -> regs
//   setprio(1): QK(kt) from Klds[c]; PV(kt-1) from pf + Vt[c^1]; setprio(0)
//   softmax(kt): max-reduce, defer-rescale (o complete thru kt-1 -> order exact),
//   exp, per-lane l-partials (cross-lane l-reduce deferred to epilogue)
//   P->Plds (wave-private), lgkm wait, pf <- Plds
// Ledger: Vt[c] written at kt, read at kt+1 (1 barrier between); Klds[c^1] glds
// at kt, read at kt+1; Vt[c^1] read at kt, rewritten at kt+1 (after S1). Epilogue
// barrier covers Vt[qb&1] block-wide visibility before the final PV.
__global__ __launch_bounds__(512, 2) void attn_kernel(const u16* __restrict__ qkv,
                                                      u16* __restrict__ outp) {
  __shared__ u16 Klds[2][64 * 128];   // 32 KB
  __shared__ u16 Vtlds[2][128 * 72];  // 36 KB
  __shared__ u16 Plds[8 * 32 * 72];   // 36 KB (per-wave 32 rows)

  const int bx = blockIdx.x;
  const int qb = 15 - (bx >> 5);      // global heavy-first ordering
  const int kh = bx & 7;
  const int b = (bx >> 3) & 3;

  const int tid = threadIdx.x;
  const int w = tid >> 6;             // 0..7
  const int lane = tid & 63;
  const int ln15 = lane & 15;
  const int quad = lane >> 4;
  const int g = w & 3;                // q-head within group
  const int half = w >> 2;            // row half (0/1)
  const int n = kh * 4 + g;

  const int ldq = 6144;
  const int seq0 = b << 10;
  const int q0 = seq0 + qb * 64;

  const u16* Qg = qkv + n * 128;
  const u16* Kg = qkv + 4096 + kh * 128;
  const u16* Vg = qkv + 5120 + kh * 128;

  // Q fragments: rf in {0,1}; A-layout row m=ln15, k=quad*8+j (q pre-scaled in rope)
  bf16x8 qf[2][4];
#pragma unroll
  for (int rf = 0; rf < 2; ++rf) {
    const u16* qrow = Qg + (size_t)(q0 + half * 32 + rf * 16 + ln15) * ldq + quad * 8;
#pragma unroll
    for (int ks = 0; ks < 4; ++ks) qf[rf][ks] = *(const bf16x8*)(qrow + ks * 32);
  }

  f32x4 o[2][8];
#pragma unroll
  for (int rf = 0; rf < 2; ++rf)
#pragma unroll
    for (int i = 0; i < 8; ++i) o[rf][i] = f32x4{0.f, 0.f, 0.f, 0.f};
  float m_r[2][4], l_r[2][4];  // l_r = per-lane partial (cols of this lane only)
#pragma unroll
  for (int rf = 0; rf < 2; ++rf)
#pragma unroll
    for (int r = 0; r < 4; ++r) { m_r[rf][r] = -INFINITY; l_r[rf][r] = 0.f; }

  // K staging: wave w covers rows w*8 + q*4 + (lane>>4), q in {0,1}; chunk-XOR
  // pre-swizzle on the global source so the linear glds dest is swizzled.
  const int kr0 = w * 8 + (lane >> 4);
  const int kr1 = kr0 + 4;
  const u16* kp0 = Kg + (size_t)(seq0 + kr0) * ldq + (((lane & 15) ^ (kr0 & 7)) << 3);
  const u16* kp1 = Kg + (size_t)(seq0 + kr1) * ldq + (((lane & 15) ^ (kr1 & 7)) << 3);

  // V staging: thread covers rows (vs0, vs0+1) x 8 h-cols starting at vhb
  const int vs0 = (tid & 31) * 2;
  const int vhb = (tid >> 5) * 8;

  union V8 { uint4 v; u16 s[8]; };
  V8 ra, rb;
  {  // prefetch V tile 0 + stage K tile 0
    const u16* v0 = Vg + (size_t)(seq0 + vs0) * ldq + vhb;
    ra.v = *(const uint4*)v0;
    rb.v = *(const uint4*)(v0 + ldq);
    glds16(kp0, &Klds[0][(w * 8) * 128]);
    glds16(kp1, &Klds[0][(w * 8 + 4) * 128]);
  }

  bf16x8 pf[2][2];  // P(kt-1) A-frags, carried across iterations

  for (int kt = 0; kt <= qb; ++kt) {
    const int cur = kt & 1;
    __syncthreads();  // S1: drains K(kt) glds + V(kt) reg loads; fences WAR/RAW

    if (kt < qb) {  // K(kt+1) glds early (async, lands before next S1)
      glds16(kp0 + (size_t)(kt + 1) * 64 * ldq, &Klds[cur ^ 1][(w * 8) * 128]);
      glds16(kp1 + (size_t)(kt + 1) * 64 * ldq, &Klds[cur ^ 1][(w * 8 + 4) * 128]);
    }
    {  // V transpose write to Vt[cur]: packed pair writes (2 lanes/bank = free)
#pragma unroll
      for (int j = 0; j < 8; ++j) {
        unsigned pk = (unsigned)ra.s[j] | ((unsigned)rb.s[j] << 16);
        *(unsigned*)&Vtlds[cur][(vhb + j) * 72 + vs0] = pk;
      }
    }
    if (kt < qb) {  // V(kt+1) reg prefetch (after ra/rb consumed)
      const u16* v0 = Vg + (size_t)(seq0 + (kt + 1) * 64 + vs0) * ldq + vhb;
      ra.v = *(const uint4*)v0;
      rb.v = *(const uint4*)(v0 + ldq);
    }

    // ---- MFMA cluster: QK(kt) + PV(kt-1) ----
    __builtin_amdgcn_s_setprio(1);
    f32x4 sfr[2][4];
#pragma unroll
    for (int rf = 0; rf < 2; ++rf)
#pragma unroll
      for (int c = 0; c < 4; ++c) {
        f32x4 acc = f32x4{0.f, 0.f, 0.f, 0.f};
#pragma unroll
        for (int ks = 0; ks < 4; ++ks) {
          int rr = c * 16 + ln15;
          int ph = (ks * 4 + quad) ^ (rr & 7);
          bf16x8 kf = *(const bf16x8*)&Klds[cur][rr * 128 + ph * 8];
          acc = __builtin_amdgcn_mfma_f32_16x16x32_bf16(qf[rf][ks], kf, acc, 0, 0, 0);
        }
        sfr[rf][c] = acc;
      }
    if (kt > 0) {  // PV(kt-1): o complete through kt-1 BEFORE softmax(kt) rescale
#pragma unroll
      for (int ht = 0; ht < 8; ++ht)
#pragma unroll
        for (int ks = 0; ks < 2; ++ks) {
          bf16x8 vf =
              *(const bf16x8*)&Vtlds[cur ^ 1][(ht * 16 + ln15) * 72 + ks * 32 + quad * 8];
#pragma unroll
          for (int rf = 0; rf < 2; ++rf)
            o[rf][ht] =
                __builtin_amdgcn_mfma_f32_16x16x32_bf16(pf[rf][ks], vf, o[rf][ht], 0, 0, 0);
        }
    }
    __builtin_amdgcn_s_setprio(0);

    if (kt == qb) {  // diagonal tile: mask col>row (offsets cancel)
#pragma unroll
      for (int rf = 0; rf < 2; ++rf)
#pragma unroll
        for (int c = 0; c < 4; ++c) {
          int col = c * 16 + ln15;
#pragma unroll
          for (int r = 0; r < 4; ++r)
            if (col > half * 32 + rf * 16 + quad * 4 + r) sfr[rf][c][r] = -INFINITY;
        }
    }

    // online softmax; row (quad*4+r) spans the 16 lanes of a quad
    float mx[2][4];
#pragma unroll
    for (int rf = 0; rf < 2; ++rf)
#pragma unroll
      for (int r = 0; r < 4; ++r) {
        float m0 = fmaxf(fmaxf(sfr[rf][0][r], sfr[rf][1][r]),
                         fmaxf(sfr[rf][2][r], sfr[rf][3][r]));
        m0 = fmaxf(m0, __shfl_xor(m0, 1));
        m0 = fmaxf(m0, __shfl_xor(m0, 2));
        m0 = fmaxf(m0, __shfl_xor(m0, 4));
        m0 = fmaxf(m0, __shfl_xor(m0, 8));
        mx[rf][r] = m0;
      }
    // T13 defer-max: rescale only when some row's max grew by > 8 (P <= e^8)
    float ex = -INFINITY;
#pragma unroll
    for (int rf = 0; rf < 2; ++rf)
#pragma unroll
      for (int r = 0; r < 4; ++r) ex = fmaxf(ex, mx[rf][r] - m_r[rf][r]);
    if (!__all(ex <= 8.f)) {
#pragma unroll
      for (int rf = 0; rf < 2; ++rf)
#pragma unroll
        for (int r = 0; r < 4; ++r) {
          float mnew = fmaxf(m_r[rf][r], mx[rf][r]);
          float al = exp2f((m_r[rf][r] - mnew) * L2E);
          m_r[rf][r] = mnew;
          l_r[rf][r] *= al;
#pragma unroll
          for (int ht = 0; ht < 8; ++ht) o[rf][ht][r] *= al;
        }
    }
#pragma unroll
    for (int rf = 0; rf < 2; ++rf)
#pragma unroll
      for (int r = 0; r < 4; ++r) {
        float rs = 0.f;
#pragma unroll
        for (int c = 0; c < 4; ++c) {
          float pv = exp2f((sfr[rf][c][r] - m_r[rf][r]) * L2E);
          sfr[rf][c][r] = pv;
          rs += pv;
        }
        l_r[rf][r] += rs;  // per-lane partial; cross-lane reduce deferred
      }

    // P: C-layout -> LDS -> A-layout (bf16); Plds region is wave-private
#pragma unroll
    for (int rf = 0; rf < 2; ++rf)
#pragma unroll
      for (int c = 0; c < 4; ++c)
#pragma unroll
        for (int r = 0; r < 4; ++r)
          Plds[w * 2304 + (rf * 16 + quad * 4 + r) * 72 + c * 16 + ln15] =
              f2bf(sfr[rf][c][r]);

    asm volatile("s_waitcnt lgkmcnt(0)" ::: "memory");

#pragma unroll
    for (int rf = 0; rf < 2; ++rf)
#pragma unroll
      for (int ks = 0; ks < 2; ++ks)
        pf[rf][ks] =
            *(const bf16x8*)&Plds[w * 2304 + (rf * 16 + ln15) * 72 + ks * 32 + quad * 8];
  }

  // epilogue: final PV(qb) after block-wide Vt[qb&1] visibility
  __syncthreads();
  {
    const int cur = qb & 1;
#pragma unroll
    for (int ht = 0; ht < 8; ++ht)
#pragma unroll
      for (int ks = 0; ks < 2; ++ks) {
        bf16x8 vf =
            *(const bf16x8*)&Vtlds[cur][(ht * 16 + ln15) * 72 + ks * 32 + quad * 8];
#pragma unroll
        for (int rf = 0; rf < 2; ++rf)
          o[rf][ht] =
              __builtin_amdgcn_mfma_f32_16x16x32_bf16(pf[rf][ks], vf, o[rf][ht], 0, 0, 0);
      }
  }

  // deferred l reduce (once): sum partials across the 16 lanes of each quad-row
#pragma unroll
  for (int rf = 0; rf < 2; ++rf)
#pragma unroll
    for (int r = 0; r < 4; ++r) {
      float s = l_r[rf][r];
      s += __shfl_xor(s, 1);
      s += __shfl_xor(s, 2);
      s += __shfl_xor(s, 4);
      s += __shfl_xor(s, 8);
      l_r[rf][r] = 1.f / s;
    }
#pragma unroll
  for (int rf = 0; rf < 2; ++rf)
#pragma unroll
    for (int ht = 0; ht < 8; ++ht)
#pragma unroll
      for (int r = 0; r < 4; ++r)
        outp[(size_t)(q0 + half * 32 + rf * 16 + quad * 4 + r) * 4096 + n * 128 +
             ht * 16 + ln15] = f2bf(o[rf][ht][r] * l_r[rf][r]);
}

// ---------------- host ----------------
extern "C" void kernel_launch(void* const* d_in, const int* in_sizes, int n_in,
                              void* d_out, int out_size, void* d_ws, size_t ws_size,
                              hipStream_t stream) {
  const float* x = (const float*)d_in[0];
  const int* posi = (const int*)d_in[1];
  const float* Wq = (const float*)d_in[2];
  const float* Wk = (const float*)d_in[3];
  const float* Wv = (const float*)d_in[4];
  const float* Wo = (const float*)d_in[5];
  float* out = (float*)d_out;
  char* ws = (char*)d_ws;

  // workspace layout (bytes); attn reuses xb region (disjoint lifetimes).
  u16* xb = (u16*)(ws);                         // [4096][4096] bf16, 33.5 MB
  u16* Wt = (u16*)(ws + 33554432);              // [6144][4096] bf16 (Wq^T|Wk^T|Wv^T), 50.3 MB
  u16* WoT = (u16*)(ws + 83886080);             // [4096][4096] bf16 (Wo^T), 33.5 MB
  u16* qkv = (u16*)(ws + 117440512);            // [4096][6144] bf16, 50.3 MB
  u16* attn = xb;                               // [4096][4096] bf16 (after x consumed)
  float2* rtab = (float2*)d_out;                // 512 KB sincos table in d_out (dead
                                                // until the final O-proj overwrites it)

  cvt_kernel<<<16384, 256, 0, stream>>>((const float4*)x, (uint2*)xb, 4194304);
  prep_kernel<<<10496, 256, 0, stream>>>(Wq, Wk, Wv, Wo, Wt, WoT, rtab);

  gemm_nt8<1, 1><<<dim3(384), 512, 0, stream>>>(xb, Wt, qkv, 4096, 6144, 4096, posi, rtab);
  attn_kernel<<<512, 512, 0, stream>>>(qkv, attn);
  gemm_nt8<0, 0><<<dim3(256), 512, 0, stream>>>(attn, WoT, out, 4096, 4096, 4096,
                                                nullptr, nullptr);
}